// Round 1
// baseline (3907.819 us; speedup 1.0000x reference)
//
#include <hip/hip_runtime.h>
#include <hip/hip_bf16.h>
#include <cstddef>

#define NN 16384
#define EE (9*NN)
#define CC 512
#define MM 32

static inline int idiv(int a, int b){ return (a+b-1)/b; }

// ---------------- utility kernels ----------------

__global__ void zero_kernel(float* __restrict__ p, int n){
    int i = blockIdx.x*blockDim.x + threadIdx.x;
    if(i<n) p[i]=0.f;
}

// column sums of F[NN][CC]; grid=128 blocks x 256 thr; cs must be pre-zeroed
__global__ void colsum_kernel(const float* __restrict__ F, float* __restrict__ cs){
    const int RPB = NN/128;
    int r0 = blockIdx.x * RPB;
    for(int c = threadIdx.x; c < CC; c += blockDim.x){
        float s = 0.f;
        for(int r=0;r<RPB;++r) s += F[(size_t)(r0+r)*CC + c];
        atomicAdd(&cs[c], s);
    }
}

// o = F - colsum/NN  (broadcast per channel)
__global__ void center_kernel(const float* __restrict__ F, const float* __restrict__ cs,
                              float* __restrict__ o){
    int i = blockIdx.x*blockDim.x + threadIdx.x;
    o[i] = F[i] - cs[i & (CC-1)] * (1.f/NN);
}

// out rows initialized to bias (Cout is power of two -> mask)
__global__ void init_rows_kernel(float* __restrict__ o, const float* __restrict__ b,
                                 int coutMask, int total){
    int i = blockIdx.x*blockDim.x + threadIdx.x;
    if(i<total) o[i] = b[i & coutMask];
}

// final output init: unzip_b[c] + sMean[c]
__global__ void init_out_kernel(float* __restrict__ o, const float* __restrict__ ub,
                                const float* __restrict__ scs){
    int i = blockIdx.x*blockDim.x + threadIdx.x;
    int c = i & (CC-1);
    o[i] = ub[c] + scs[c]*(1.f/NN);
}

__global__ void relu_kernel(float* __restrict__ p, int n){
    int i = blockIdx.x*blockDim.x + threadIdx.x;
    if(i<n) p[i] = fmaxf(p[i], 0.f);
}

// ---------------- SGEMM: C[M,N] = A[M,K] @ B[K,N], row-major ----------------
// M % BM == 0, K % BK == 0 assumed (true for all our shapes); N guarded.
template<int BM, int BN, int BK, int TM, int TN>
__global__ void sgemm(int M, int N, int K,
                      const float* __restrict__ A, const float* __restrict__ B,
                      float* __restrict__ C){
    __shared__ float As[BK][BM+4];
    __shared__ float Bs[BK][BN+4];
    const int tcols = BN/TN;                 // 16
    const int tid = threadIdx.x;
    const int tr = tid / tcols;
    const int tc = tid % tcols;
    const int row0 = blockIdx.y * BM;
    const int col0 = blockIdx.x * BN;
    float acc[TM][TN] = {};
    for (int k0 = 0; k0 < K; k0 += BK){
        for (int i = tid; i < BM*BK; i += blockDim.x){
            int m = i / BK, k = i % BK;
            As[k][m] = A[(size_t)(row0+m)*K + k0 + k];
        }
        for (int i = tid; i < BK*BN; i += blockDim.x){
            int k = i / BN, n = i % BN;
            float v = 0.f;
            if (col0 + n < N) v = B[(size_t)(k0+k)*N + col0 + n];
            Bs[k][n] = v;
        }
        __syncthreads();
        #pragma unroll
        for (int k = 0; k < BK; ++k){
            float ra[TM], rb[TN];
            #pragma unroll
            for (int i=0;i<TM;++i) ra[i] = As[k][tr*TM+i];
            #pragma unroll
            for (int j=0;j<TN;++j) rb[j] = Bs[k][tc*TN+j];
            #pragma unroll
            for (int i=0;i<TM;++i)
                #pragma unroll
                for (int j=0;j<TN;++j)
                    acc[i][j] += ra[i]*rb[j];
        }
        __syncthreads();
    }
    #pragma unroll
    for (int i=0;i<TM;++i){
        int r = row0 + tr*TM + i;
        #pragma unroll
        for (int j=0;j<TN;++j){
            int c = col0 + tc*TN + j;
            if (c < N) C[(size_t)r*N + c] = acc[i][j];
        }
    }
}

// ---------------- scatter-add: out[dst[e]] += t[src[e]] for edges with sel==s ----------------
__global__ void scatter_kernel(const int* __restrict__ src, const int* __restrict__ dst,
                               const int* __restrict__ sel, int E, int s,
                               const float* __restrict__ t, float* __restrict__ out, int Cout){
    int wave = (blockIdx.x*blockDim.x + threadIdx.x) >> 6;
    int lane = threadIdx.x & 63;
    int nwaves = (gridDim.x*blockDim.x) >> 6;
    for (int e = wave; e < E; e += nwaves){
        if (sel[e] != s) continue;
        const float* trow = t + (size_t)src[e]*Cout;
        float* orow = out + (size_t)dst[e]*Cout;
        for (int c = lane; c < Cout; c += 64)
            atomicAdd(&orow[c], trow[c]);
    }
}

// ---------------- gram: g[i*32+j] += sum_n h[n,i]*h[n,j]  (scaled later by 1/NN) ----------------
__global__ void gram_kernel(const float* __restrict__ h, float* __restrict__ g){
    const int RPB = NN/64;                    // launched with 64 blocks
    int r0 = blockIdx.x*RPB;
    int i = threadIdx.x >> 5, j = threadIdx.x & 31;  // 1024 threads
    float s = 0.f;
    for (int r = 0; r < RPB; ++r){
        const float* row = h + (size_t)(r0+r)*32;
        s += row[i]*row[j];
    }
    atomicAdd(&g[threadIdx.x], s);
}

// ---------------- fc: outMat[i] = fcb[i] + sum_j (g[j]/NN) * fcW[i*1024+j] ----------------
__global__ void fc_kernel(const float* __restrict__ g, const float* __restrict__ fcW,
                          const float* __restrict__ fcb, float* __restrict__ outMat){
    int i = blockIdx.x;
    float s = 0.f;
    for (int j = threadIdx.x; j < 1024; j += 256)
        s += g[j] * (1.f/NN) * fcW[(size_t)i*1024 + j];
    __shared__ float red[256];
    red[threadIdx.x] = s; __syncthreads();
    for (int off = 128; off > 0; off >>= 1){
        if (threadIdx.x < off) red[threadIdx.x] += red[threadIdx.x+off];
        __syncthreads();
    }
    if (threadIdx.x == 0) outMat[i] = red[0] + fcb[i];
}

// ---------------- T = A(32x32) @ B(32x32) ----------------
__global__ void mm32_kernel(const float* __restrict__ A, const float* __restrict__ B,
                            float* __restrict__ T){
    int i = threadIdx.x >> 5, j = threadIdx.x & 31;
    float s = 0.f;
    for (int k = 0; k < 32; ++k) s += A[i*32+k]*B[k*32+j];
    T[threadIdx.x] = s;
}

// ---------------- tf[n,i] = sum_j cc[n,j] * T[i,j]  (cc @ T^T) ----------------
__global__ void tf_kernel(const float* __restrict__ cc, const float* __restrict__ T,
                          float* __restrict__ tfo){
    __shared__ float Ts[1024];
    for (int i = threadIdx.x; i < 1024; i += blockDim.x) Ts[i] = T[i];
    __syncthreads();
    int idx = blockIdx.x*blockDim.x + threadIdx.x;   // over NN*32
    int n = idx >> 5, i = idx & 31;
    float s = 0.f;
    const float* crow = cc + (size_t)n*32;
    #pragma unroll
    for (int j = 0; j < 32; ++j) s += crow[j] * Ts[i*32+j];
    tfo[idx] = s;
}

// ---------------- one cnn_net ----------------
static void run_net(hipStream_t stream, const float* x,
                    const int* src, const int* dst, const int* sel,
                    const float* W1, const float* b1, const float* W2, const float* b2,
                    const float* W3, const float* b3, const float* fcW, const float* fcb,
                    float* h1, float* h2, float* h3, float* tbuf, float* g, float* outMat){
    // layer 1: [NN,512] -> [NN,256]
    init_rows_kernel<<<idiv(NN*256,256),256,0,stream>>>(h1,b1,255,NN*256);
    for(int s=0;s<9;++s){
        sgemm<64,64,16,4,4><<<dim3(4,NN/64),256,0,stream>>>(NN,256,512,x,W1+(size_t)s*512*256,tbuf);
        scatter_kernel<<<2048,256,0,stream>>>(src,dst,sel,EE,s,tbuf,h1,256);
    }
    relu_kernel<<<idiv(NN*256,256),256,0,stream>>>(h1,NN*256);
    // layer 2: [NN,256] -> [NN,128]
    init_rows_kernel<<<idiv(NN*128,256),256,0,stream>>>(h2,b2,127,NN*128);
    for(int s=0;s<9;++s){
        sgemm<64,64,16,4,4><<<dim3(2,NN/64),256,0,stream>>>(NN,128,256,h1,W2+(size_t)s*256*128,tbuf);
        scatter_kernel<<<2048,256,0,stream>>>(src,dst,sel,EE,s,tbuf,h2,128);
    }
    relu_kernel<<<idiv(NN*128,256),256,0,stream>>>(h2,NN*128);
    // layer 3: [NN,128] -> [NN,32]
    init_rows_kernel<<<idiv(NN*32,256),256,0,stream>>>(h3,b3,31,NN*32);
    for(int s=0;s<9;++s){
        sgemm<64,64,16,4,4><<<dim3(1,NN/64),256,0,stream>>>(NN,32,128,h2,W3+(size_t)s*128*32,tbuf);
        scatter_kernel<<<2048,256,0,stream>>>(src,dst,sel,EE,s,tbuf,h3,32);
    }
    // gram + fc (g pre-zeroed)
    gram_kernel<<<64,1024,0,stream>>>(h3,g);
    fc_kernel<<<1024,256,0,stream>>>(g,fcW,fcb,outMat);
}

extern "C" void kernel_launch(void* const* d_in, const int* in_sizes, int n_in,
                              void* d_out, int out_size, void* d_ws, size_t ws_size,
                              hipStream_t stream){
    const float* cF   = (const float*)d_in[0];
    const float* sF   = (const float*)d_in[1];
    const int*   cEI  = (const int*)d_in[2];
    const int*   cSel = (const int*)d_in[3];
    const int*   sEI  = (const int*)d_in[4];
    const int*   sSel = (const int*)d_in[5];
    const float* compW= (const float*)d_in[6];
    const float* compB= (const float*)d_in[7];
    const float* unzW = (const float*)d_in[8];
    const float* unzB = (const float*)d_in[9];
    const float* cW1=(const float*)d_in[10]; const float* cB1=(const float*)d_in[11];
    const float* cW2=(const float*)d_in[12]; const float* cB2=(const float*)d_in[13];
    const float* cW3=(const float*)d_in[14]; const float* cB3=(const float*)d_in[15];
    const float* cFW=(const float*)d_in[16]; const float* cFB=(const float*)d_in[17];
    const float* sW1=(const float*)d_in[18]; const float* sB1=(const float*)d_in[19];
    const float* sW2=(const float*)d_in[20]; const float* sB2=(const float*)d_in[21];
    const float* sW3=(const float*)d_in[22]; const float* sB3=(const float*)d_in[23];
    const float* sFW=(const float*)d_in[24]; const float* sFB=(const float*)d_in[25];

    float* out  = (float*)d_out;                 // [NN*CC] ...
    float* Tmat = out + (size_t)NN*CC;           // ... then [32*32]

    // workspace layout (floats). total ~28.9M floats ~ 116 MB.
    float* ws   = (float*)d_ws;
    float* cCol = ws + 0;        // 512
    float* sCol = ws + 512;      // 512
    float* cg   = ws + 1024;     // 1024
    float* sg   = ws + 2048;     // 1024
    float* cMat = ws + 3072;     // 1024
    float* sMat = ws + 4096;     // 1024
    float* cFc  = ws + 8192;                       // NN*CC
    float* sFc  = cFc + (size_t)NN*CC;             // NN*CC
    float* h1   = sFc + (size_t)NN*CC;             // NN*256
    float* h2   = h1  + (size_t)NN*256;            // NN*128
    float* h3   = h2  + (size_t)NN*128;            // NN*32
    float* tbuf = h3  + (size_t)NN*32;             // NN*256 (per-selection GEMM out)
    float* cc   = tbuf+ (size_t)NN*256;            // NN*32 compress_content
    float* tfb  = cc  + (size_t)NN*32;             // NN*32 transfeature
    float* tu   = cFc;                             // reuse cFc for unzip temp [NN,CC]

    const int* cSrc = cEI; const int* cDst = cEI + EE;
    const int* sSrc = sEI; const int* sDst = sEI + EE;

    // zero the small accumulators (colsums + grams)
    zero_kernel<<<idiv(3072,256),256,0,stream>>>(ws, 3072);

    // means + centering
    colsum_kernel<<<128,256,0,stream>>>(cF, cCol);
    colsum_kernel<<<128,256,0,stream>>>(sF, sCol);
    center_kernel<<<NN*CC/256,256,0,stream>>>(cF, cCol, cFc);
    center_kernel<<<NN*CC/256,256,0,stream>>>(sF, sCol, sFc);

    // compress_content = sel_conv(cFc, content, S=1) : only sel==0 edges
    init_rows_kernel<<<idiv(NN*32,256),256,0,stream>>>(cc, compB, 31, NN*32);
    sgemm<64,64,16,4,4><<<dim3(1,NN/64),256,0,stream>>>(NN,32,CC,cFc,compW,tbuf);
    scatter_kernel<<<2048,256,0,stream>>>(cSrc,cDst,cSel,EE,0,tbuf,cc,32);

    // cnet / snet
    run_net(stream, cFc, cSrc,cDst,cSel, cW1,cB1,cW2,cB2,cW3,cB3,cFW,cFB, h1,h2,h3,tbuf,cg,cMat);
    run_net(stream, sFc, sSrc,sDst,sSel, sW1,sB1,sW2,sB2,sW3,sB3,sFW,sFB, h1,h2,h3,tbuf,sg,sMat);

    // transmatrix = sMat @ cMat  -> second output
    mm32_kernel<<<1,1024,0,stream>>>(sMat,cMat,Tmat);

    // transfeature = compress_content @ T^T
    tf_kernel<<<NN*32/256,256,0,stream>>>(cc, Tmat, tfb);

    // unzip: t = tf @ unzip_W[0] ; out = unzip_b + sMean + scatter(sel==0)
    sgemm<64,64,16,4,4><<<dim3(8,NN/64),256,0,stream>>>(NN,CC,32,tfb,unzW,tu);
    init_out_kernel<<<NN*CC/256,256,0,stream>>>(out, unzB, sCol);
    scatter_kernel<<<2048,256,0,stream>>>(cSrc,cDst,cSel,EE,0,tu,out,CC);
}

// Round 2
// 759.845 us; speedup vs baseline: 5.1429x; 5.1429x over previous
//
#include <hip/hip_runtime.h>
#include <hip/hip_bf16.h>
#include <cstddef>
#include <cstdint>

#define NN 16384
#define EE (9*NN)
#define CC 512

typedef __attribute__((ext_vector_type(4))) float f32x4;
typedef __attribute__((ext_vector_type(8))) short bf16x8;

static inline int idiv(int a, int b){ return (a+b-1)/b; }

__device__ __forceinline__ float bf2f(unsigned short u){
    union{unsigned u; float f;} v; v.u = ((unsigned)u) << 16; return v.f;
}
__device__ __forceinline__ unsigned short f2bf(float f){
    union{float f; unsigned u;} v; v.f = f;
    unsigned r = v.u + 0x7fffu + ((v.u >> 16) & 1u);
    return (unsigned short)(r >> 16);
}

__device__ __forceinline__ void gload16(const void* gsrc, void* ldst){
    __builtin_amdgcn_global_load_lds(
        (const __attribute__((address_space(1))) unsigned int*)gsrc,
        (__attribute__((address_space(3))) unsigned int*)ldst,
        16, 0, 0);
}

// ---------------- utility kernels ----------------

__global__ void zero_f(float* __restrict__ p, int n){
    int i = blockIdx.x*256 + threadIdx.x; if (i < n) p[i] = 0.f;
}
__global__ void zero_i(int* __restrict__ p, int n){
    int i = blockIdx.x*256 + threadIdx.x; if (i < n) p[i] = 0;
}

// column sums of F[NN][CC]; cs pre-zeroed
__global__ void colsum_kernel(const float* __restrict__ F, float* __restrict__ cs){
    const int RPB = NN/128;
    int r0 = blockIdx.x * RPB;
    for (int c = threadIdx.x; c < CC; c += blockDim.x){
        float s = 0.f;
        for (int r = 0; r < RPB; ++r) s += F[(size_t)(r0+r)*CC + c];
        atomicAdd(&cs[c], s);
    }
}

// o = bf16(F - colsum/NN)
__global__ void center_cvt(const float* __restrict__ F, const float* __restrict__ cs,
                           unsigned short* __restrict__ o){
    int i = blockIdx.x*256 + threadIdx.x;
    o[i] = f2bf(F[i] - cs[i & (CC-1)] * (1.f/NN));
}

// W[S][K][Cout] fp32 -> Wt[Npad][Kpad] bf16 (Wt[s*Cout+j][k] = W[s][k][j]; zero pad)
__global__ void wtrans(const float* __restrict__ W, unsigned short* __restrict__ Wt,
                       int S, int K, int Cout, int Npad, int Kpad){
    int idx = blockIdx.x*256 + threadIdx.x;
    if (idx >= Npad*Kpad) return;
    int colp = idx / Kpad, k = idx - colp*Kpad;
    int s = colp / Cout, j = colp - s*Cout;
    float v = 0.f;
    if (s < S && k < K) v = W[((size_t)s*K + k)*Cout + j];
    Wt[idx] = f2bf(v);
}

// ---------------- CSR build (per graph) ----------------
__global__ void csr_count(const int* __restrict__ dst, int* __restrict__ cnt){
    int e = blockIdx.x*256 + threadIdx.x;
    if (e < EE) atomicAdd(&cnt[dst[e]], 1);
}
__global__ void csr_scan(const int* __restrict__ cnt, int* __restrict__ rowptr){
    __shared__ int part[1024];
    int t = threadIdx.x;
    int base = t*16, s = 0;
    int local[16];
    #pragma unroll
    for (int i = 0; i < 16; ++i){ local[i] = s; s += cnt[base+i]; }
    part[t] = s; __syncthreads();
    for (int off = 1; off < 1024; off <<= 1){
        int v = (t >= off) ? part[t-off] : 0;
        __syncthreads();
        part[t] += v;
        __syncthreads();
    }
    int pre = (t == 0) ? 0 : part[t-1];
    #pragma unroll
    for (int i = 0; i < 16; ++i) rowptr[base+i] = pre + local[i];
    if (t == 1023) rowptr[NN] = part[1023];
}
__global__ void csr_fill(const int* __restrict__ src, const int* __restrict__ dst,
                         const int* __restrict__ sel, const int* __restrict__ rowptr,
                         int* __restrict__ cur, int* __restrict__ elist){
    int e = blockIdx.x*256 + threadIdx.x;
    if (e >= EE) return;
    int d = dst[e];
    int p = atomicAdd(&cur[d], 1);
    elist[rowptr[d] + p] = (src[e] << 4) | sel[e];
}

// ---------------- MFMA GEMM: C[M,N] = A[M,K] @ Bt[N,K]^T, bf16 in, fp32 acc ----------------
// M multiple of 128 (grid.y), N multiple of 128 (grid.x), K multiple of 64.
template<typename OutT>
__global__ __launch_bounds__(256, 2)
void mfma_gemm(const unsigned short* __restrict__ A, const unsigned short* __restrict__ Bt,
               OutT* __restrict__ C, int K, int N){
    __shared__ __align__(16) unsigned short As[128*64];
    __shared__ __align__(16) unsigned short Bs[128*64];
    const int tid  = threadIdx.x;
    const int wave = tid >> 6, lane = tid & 63;
    const int row0 = blockIdx.y << 7, col0 = blockIdx.x << 7;
    const int wm = wave >> 1, wn = wave & 1;
    const int fr = lane & 15, fq = lane >> 4;
    f32x4 acc[4][4] = {};
    for (int k0 = 0; k0 < K; k0 += 64){
        __syncthreads();
        #pragma unroll
        for (int i = 0; i < 4; ++i){
            int chb = (wave*4 + i) * 64;              // wave-uniform chunk base
            int ch  = chb + lane;
            int r   = ch >> 3, c8 = ch & 7;           // row in tile, 16B-chunk in row
            gload16((const char*)(A  + (size_t)(row0 + r)*K + k0) + c8*16, As + chb*8);
            gload16((const char*)(Bt + (size_t)(col0 + r)*K + k0) + c8*16, Bs + chb*8);
        }
        __syncthreads();
        #pragma unroll
        for (int ks = 0; ks < 2; ++ks){
            bf16x8 av[4], bv[4];
            #pragma unroll
            for (int m = 0; m < 4; ++m)
                av[m] = *(const bf16x8*)(As + ((wm<<6)+(m<<4)+fr)*64 + (ks<<5) + (fq<<3));
            #pragma unroll
            for (int n = 0; n < 4; ++n)
                bv[n] = *(const bf16x8*)(Bs + ((wn<<6)+(n<<4)+fr)*64 + (ks<<5) + (fq<<3));
            #pragma unroll
            for (int m = 0; m < 4; ++m)
                #pragma unroll
                for (int n = 0; n < 4; ++n)
                    acc[m][n] = __builtin_amdgcn_mfma_f32_16x16x32_bf16(av[m], bv[n], acc[m][n], 0, 0, 0);
        }
    }
    #pragma unroll
    for (int m = 0; m < 4; ++m){
        #pragma unroll
        for (int r = 0; r < 4; ++r){
            int row = row0 + (wm<<6) + (m<<4) + (fq<<2) + r;
            OutT* crow = C + (size_t)row*N + col0 + (wn<<6) + fr;
            #pragma unroll
            for (int n = 0; n < 4; ++n){
                float v = acc[m][n][r];
                if constexpr (sizeof(OutT) == 2) crow[n<<4] = f2bf(v);
                else                             crow[n<<4] = v;
            }
        }
    }
}

// ---------------- CSR gather: out[d,c] = init + sum_{e in(d), sel<S, src in range} t[src, sel*Cout+c] ----------------
template<typename TI, typename TO, bool RELU>
__global__ void gather_k(const int* __restrict__ rowptr, const int* __restrict__ elist,
                         const TI* __restrict__ t, const float* __restrict__ bias,
                         const float* __restrict__ initBuf, const float* __restrict__ addvec,
                         TO* __restrict__ out, int tStride, int coutShift, int S,
                         int srcLo, int srcHi){
    int idx = blockIdx.x*256 + threadIdx.x;
    int d = idx >> coutShift;
    int c = idx & ((1 << coutShift) - 1);
    float acc = initBuf ? initBuf[idx] : bias[c];
    int j1 = rowptr[d+1];
    for (int j = rowptr[d]; j < j1; ++j){
        int p = elist[j];
        int s = p & 15, sr = p >> 4;
        if (s < S && sr >= srcLo && sr < srcHi){
            TI v = t[(size_t)(sr - srcLo)*tStride + (s << coutShift) + c];
            if constexpr (sizeof(TI) == 2) acc += bf2f((unsigned short)v);
            else                           acc += v;
        }
    }
    if (addvec) acc += addvec[c] * (1.f/NN);
    if (RELU) acc = fmaxf(acc, 0.f);
    if constexpr (sizeof(TO) == 2) out[idx] = f2bf(acc);
    else                           out[idx] = acc;
}

// ---------------- gram / fc / 32x32 ops (fp32, verified round 1) ----------------
__global__ void gram_kernel(const float* __restrict__ h, float* __restrict__ g){
    const int RPB = NN/64;
    int r0 = blockIdx.x*RPB;
    int i = threadIdx.x >> 5, j = threadIdx.x & 31;
    float s = 0.f;
    for (int r = 0; r < RPB; ++r){
        const float* row = h + (size_t)(r0+r)*32;
        s += row[i]*row[j];
    }
    atomicAdd(&g[threadIdx.x], s);
}

__global__ void fc_kernel(const float* __restrict__ g, const float* __restrict__ fcW,
                          const float* __restrict__ fcb, float* __restrict__ outMat){
    int i = blockIdx.x;
    float s = 0.f;
    for (int j = threadIdx.x; j < 1024; j += 256)
        s += g[j] * (1.f/NN) * fcW[(size_t)i*1024 + j];
    __shared__ float red[256];
    red[threadIdx.x] = s; __syncthreads();
    for (int off = 128; off > 0; off >>= 1){
        if (threadIdx.x < off) red[threadIdx.x] += red[threadIdx.x+off];
        __syncthreads();
    }
    if (threadIdx.x == 0) outMat[i] = red[0] + fcb[i];
}

__global__ void mm32_kernel(const float* __restrict__ A, const float* __restrict__ B,
                            float* __restrict__ T){
    int i = threadIdx.x >> 5, j = threadIdx.x & 31;
    float s = 0.f;
    for (int k = 0; k < 32; ++k) s += A[i*32+k]*B[k*32+j];
    T[threadIdx.x] = s;
}

__global__ void tf_kernel(const float* __restrict__ cc, const float* __restrict__ T,
                          float* __restrict__ tfo){
    __shared__ float Ts[1024];
    for (int i = threadIdx.x; i < 1024; i += blockDim.x) Ts[i] = T[i];
    __syncthreads();
    int idx = blockIdx.x*blockDim.x + threadIdx.x;
    int n = idx >> 5, i = idx & 31;
    float s = 0.f;
    const float* crow = cc + (size_t)n*32;
    #pragma unroll
    for (int j = 0; j < 32; ++j) s += crow[j] * Ts[i*32+j];
    tfo[idx] = s;
}

// tfb fp32 [NN][32] -> bf16 [NN][64] zero-padded in k
__global__ void cvt_pad(const float* __restrict__ f, unsigned short* __restrict__ b){
    int idx = blockIdx.x*256 + threadIdx.x;
    int n = idx >> 6, k = idx & 63;
    b[idx] = f2bf(k < 32 ? f[(n<<5) + k] : 0.f);
}

// ---------------- one cnn_net ----------------
static void run_net(hipStream_t st, const unsigned short* xB,
                    const int* rowptr, const int* elist,
                    const unsigned short* W1t, const float* b1,
                    const unsigned short* W2t, const float* b2,
                    const unsigned short* W3t, const float* b3,
                    const float* fcW, const float* fcb,
                    unsigned short* tB,
                    float* h1f, unsigned short* h1b, unsigned short* h2b, float* h3f,
                    float* g, float* outMat){
    // L1: [NN,512] -> 9x256, M split in halves (t buffer = 8192 x 2304 bf16)
    mfma_gemm<unsigned short><<<dim3(18,64),256,0,st>>>(xB, W1t, tB, 512, 2304);
    gather_k<unsigned short,float,false><<<NN,256,0,st>>>(rowptr,elist,tB,b1,nullptr,nullptr,h1f,2304,8,9,0,8192);
    mfma_gemm<unsigned short><<<dim3(18,64),256,0,st>>>(xB + (size_t)8192*512, W1t, tB, 512, 2304);
    gather_k<unsigned short,unsigned short,true><<<NN,256,0,st>>>(rowptr,elist,tB,nullptr,h1f,nullptr,h1b,2304,8,9,8192,16384);
    // L2: [NN,256] -> 9x128
    mfma_gemm<unsigned short><<<dim3(9,128),256,0,st>>>(h1b, W2t, tB, 256, 1152);
    gather_k<unsigned short,unsigned short,true><<<NN/2,256,0,st>>>(rowptr,elist,tB,b2,nullptr,nullptr,h2b,1152,7,9,0,16384);
    // L3: [NN,128] -> 9x32 (padded to 384)
    mfma_gemm<unsigned short><<<dim3(3,128),256,0,st>>>(h2b, W3t, tB, 128, 384);
    gather_k<unsigned short,float,false><<<NN/8,256,0,st>>>(rowptr,elist,tB,b3,nullptr,nullptr,h3f,384,5,9,0,16384);
    // gram + fc (g pre-zeroed)
    gram_kernel<<<64,1024,0,st>>>(h3f,g);
    fc_kernel<<<1024,256,0,st>>>(g,fcW,fcb,outMat);
}

extern "C" void kernel_launch(void* const* d_in, const int* in_sizes, int n_in,
                              void* d_out, int out_size, void* d_ws, size_t ws_size,
                              hipStream_t stream){
    const float* cF   = (const float*)d_in[0];
    const float* sF   = (const float*)d_in[1];
    const int*   cEI  = (const int*)d_in[2];
    const int*   cSel = (const int*)d_in[3];
    const int*   sEI  = (const int*)d_in[4];
    const int*   sSel = (const int*)d_in[5];
    const float* compW= (const float*)d_in[6];
    const float* compB= (const float*)d_in[7];
    const float* unzW = (const float*)d_in[8];
    const float* unzB = (const float*)d_in[9];
    const float* cW1=(const float*)d_in[10]; const float* cB1=(const float*)d_in[11];
    const float* cW2=(const float*)d_in[12]; const float* cB2=(const float*)d_in[13];
    const float* cW3=(const float*)d_in[14]; const float* cB3=(const float*)d_in[15];
    const float* cFW=(const float*)d_in[16]; const float* cFB=(const float*)d_in[17];
    const float* sW1=(const float*)d_in[18]; const float* sB1=(const float*)d_in[19];
    const float* sW2=(const float*)d_in[20]; const float* sB2=(const float*)d_in[21];
    const float* sW3=(const float*)d_in[22]; const float* sB3=(const float*)d_in[23];
    const float* sFW=(const float*)d_in[24]; const float* sFB=(const float*)d_in[25];

    float* out  = (float*)d_out;
    float* Tmat = out + (size_t)NN*CC;

    // ---- workspace carve (deterministic; total ~104.4 MB) ----
    char* w = (char*)d_ws;
    auto alloc = [&](size_t b)->char*{ char* p = w; w += (b + 255) & ~(size_t)255; return p; };
    float* cCol = (float*)alloc(512*4);
    float* sCol = (float*)alloc(512*4);
    float* cg   = (float*)alloc(1024*4);
    float* sg   = (float*)alloc(1024*4);
    float* cMat = (float*)alloc(1024*4);
    float* sMat = (float*)alloc(1024*4);
    int* cCnt = (int*)alloc(NN*4);
    int* cCur = (int*)alloc(NN*4);
    int* sCnt = (int*)alloc(NN*4);
    int* sCur = (int*)alloc(NN*4);
    int* cRow = (int*)alloc((NN+1)*4);
    int* sRow = (int*)alloc((NN+1)*4);
    int* cEl  = (int*)alloc(EE*4);
    int* sEl  = (int*)alloc(EE*4);
    float* tfb   = (float*)alloc((size_t)NN*32*4);
    float* ccbuf = (float*)alloc((size_t)NN*32*4);
    unsigned short* tfbB = (unsigned short*)alloc((size_t)NN*64*2);
    unsigned short* wtC1 = (unsigned short*)alloc((size_t)2304*512*2);
    unsigned short* wtC2 = (unsigned short*)alloc((size_t)1152*256*2);
    unsigned short* wtC3 = (unsigned short*)alloc((size_t)384*128*2);
    unsigned short* wtS1 = (unsigned short*)alloc((size_t)2304*512*2);
    unsigned short* wtS2 = (unsigned short*)alloc((size_t)1152*256*2);
    unsigned short* wtS3 = (unsigned short*)alloc((size_t)384*128*2);
    unsigned short* wtCo = (unsigned short*)alloc((size_t)128*512*2);
    unsigned short* wtU  = (unsigned short*)alloc((size_t)512*64*2);
    unsigned short* cFcB = (unsigned short*)alloc((size_t)NN*512*2);   // region A
    unsigned short* sFcB = (unsigned short*)alloc((size_t)NN*512*2);
    float* h1f = (float*)alloc((size_t)NN*256*4);
    float* h3f = (float*)alloc((size_t)NN*32*4);
    char*  treg = alloc((size_t)16384*1152*2);                          // 37.75 MB, multi-use
    unsigned short* tB = (unsigned short*)treg;
    float*          tF = (float*)treg;
    // overlays in region A (cFcB dead after its last GEMM use)
    unsigned short* h1b = cFcB;
    unsigned short* h2b = cFcB + (size_t)NN*256;

    const int* cSrc = cEI; const int* cDst = cEI + EE;
    const int* sSrc = sEI; const int* sDst = sEI + EE;

    // ---- zero accumulators ----
    zero_f<<<12,256,0,stream>>>((float*)d_ws, 3072);      // cCol,sCol,cg,sg
    zero_i<<<256,256,0,stream>>>(cCnt, 4*NN);             // cCnt,cCur,sCnt,sCur (contiguous)

    // ---- means + centering (bf16 out) ----
    colsum_kernel<<<128,256,0,stream>>>(cF, cCol);
    colsum_kernel<<<128,256,0,stream>>>(sF, sCol);
    center_cvt<<<NN*CC/256,256,0,stream>>>(cF, cCol, cFcB);
    center_cvt<<<NN*CC/256,256,0,stream>>>(sF, sCol, sFcB);

    // ---- weight transposes (bf16, padded) ----
    wtrans<<<idiv(2304*512,256),256,0,stream>>>(cW1, wtC1, 9,512,256, 2304,512);
    wtrans<<<idiv(1152*256,256),256,0,stream>>>(cW2, wtC2, 9,256,128, 1152,256);
    wtrans<<<idiv(384*128,256),256,0,stream>>>(cW3, wtC3, 9,128,32,  384,128);
    wtrans<<<idiv(2304*512,256),256,0,stream>>>(sW1, wtS1, 9,512,256, 2304,512);
    wtrans<<<idiv(1152*256,256),256,0,stream>>>(sW2, wtS2, 9,256,128, 1152,256);
    wtrans<<<idiv(384*128,256),256,0,stream>>>(sW3, wtS3, 9,128,32,  384,128);
    wtrans<<<idiv(128*512,256),256,0,stream>>>(compW, wtCo, 1,512,32, 128,512);
    wtrans<<<idiv(512*64,256),256,0,stream>>>(unzW,  wtU,  1,32,512, 512,64);

    // ---- CSR build (content + style) ----
    csr_count<<<idiv(EE,256),256,0,stream>>>(cDst, cCnt);
    csr_scan<<<1,1024,0,stream>>>(cCnt, cRow);
    csr_fill<<<idiv(EE,256),256,0,stream>>>(cSrc, cDst, cSel, cRow, cCur, cEl);
    csr_count<<<idiv(EE,256),256,0,stream>>>(sDst, sCnt);
    csr_scan<<<1,1024,0,stream>>>(sCnt, sRow);
    csr_fill<<<idiv(EE,256),256,0,stream>>>(sSrc, sDst, sSel, sRow, sCur, sEl);

    // ---- compress: cc = bias + gather(sel==0) of cFc @ compW ----
    mfma_gemm<float><<<dim3(1,128),256,0,stream>>>(cFcB, wtCo, tF, 512, 128);
    gather_k<float,float,false><<<NN/8,256,0,stream>>>(cRow,cEl,tF,compB,nullptr,nullptr,ccbuf,128,5,1,0,NN);

    // ---- nets ----
    run_net(stream, cFcB, cRow, cEl, wtC1,cB1, wtC2,cB2, wtC3,cB3, cFW,cFB,
            tB, h1f, h1b, h2b, h3f, cg, cMat);
    run_net(stream, sFcB, sRow, sEl, wtS1,sB1, wtS2,sB2, wtS3,sB3, sFW,sFB,
            tB, h1f, h1b, h2b, h3f, sg, sMat);

    // ---- transmatrix + transfeature ----
    mm32_kernel<<<1,1024,0,stream>>>(sMat, cMat, Tmat);
    tf_kernel<<<NN*32/256,256,0,stream>>>(ccbuf, Tmat, tfb);
    cvt_pad<<<NN*64/256,256,0,stream>>>(tfb, tfbB);

    // ---- unzip: out = unzip_b + sMean + gather(sel==0) of tf @ unzip_W ----
    mfma_gemm<float><<<dim3(4,128),256,0,stream>>>(tfbB, wtU, tF, 64, 512);
    gather_k<float,float,false><<<NN*2,256,0,stream>>>(cRow,cEl,tF,unzB,nullptr,sCol,out,512,9,1,0,NN);
}

// Round 3
// 569.666 us; speedup vs baseline: 6.8598x; 1.3338x over previous
//
#include <hip/hip_runtime.h>
#include <hip/hip_bf16.h>
#include <cstddef>
#include <cstdint>

#define NN 16384
#define EE (9*NN)
#define CC 512

typedef __attribute__((ext_vector_type(4))) float f32x4;
typedef __attribute__((ext_vector_type(8))) short bf16x8;

static inline int idiv(int a, int b){ return (a+b-1)/b; }

__device__ __forceinline__ float bf2f(unsigned short u){
    union{unsigned u; float f;} v; v.u = ((unsigned)u) << 16; return v.f;
}
__device__ __forceinline__ unsigned short f2bf(float f){
    union{float f; unsigned u;} v; v.f = f;
    unsigned r = v.u + 0x7fffu + ((v.u >> 16) & 1u);
    return (unsigned short)(r >> 16);
}

__device__ __forceinline__ void gload16(const void* gsrc, void* ldst){
    __builtin_amdgcn_global_load_lds(
        (const __attribute__((address_space(1))) unsigned int*)gsrc,
        (__attribute__((address_space(3))) unsigned int*)ldst,
        16, 0, 0);
}

// ---------------- utility kernels ----------------

__global__ void zero_f(float* __restrict__ p, int n){
    int i = blockIdx.x*256 + threadIdx.x; if (i < n) p[i] = 0.f;
}
__global__ void zero_i(int* __restrict__ p, int n){
    int i = blockIdx.x*256 + threadIdx.x; if (i < n) p[i] = 0;
}

// column sums of F[NN][CC] via float4; cs pre-zeroed. 256 blocks x 128 thr.
__global__ void colsum4(const float* __restrict__ F, float* __restrict__ cs){
    const int RPB = NN/256;
    int r0 = blockIdx.x * RPB;
    int c4 = threadIdx.x;                     // 0..127
    float4 s = {0.f,0.f,0.f,0.f};
    for (int r = 0; r < RPB; ++r){
        float4 v = ((const float4*)(F + (size_t)(r0+r)*CC))[c4];
        s.x += v.x; s.y += v.y; s.z += v.z; s.w += v.w;
    }
    atomicAdd(&cs[c4*4+0], s.x);
    atomicAdd(&cs[c4*4+1], s.y);
    atomicAdd(&cs[c4*4+2], s.z);
    atomicAdd(&cs[c4*4+3], s.w);
}

// o = bf16(F - colsum/NN), 4 elems/thread
__global__ void center_cvt4(const float* __restrict__ F, const float* __restrict__ cs,
                            ushort4* __restrict__ o){
    int i = blockIdx.x*256 + threadIdx.x;
    float4 v = ((const float4*)F)[i];
    int c = (i << 2) & (CC-1);
    float4 m = *(const float4*)(cs + c);
    ushort4 r;
    r.x = f2bf(v.x - m.x*(1.f/NN));
    r.y = f2bf(v.y - m.y*(1.f/NN));
    r.z = f2bf(v.z - m.z*(1.f/NN));
    r.w = f2bf(v.w - m.w*(1.f/NN));
    o[i] = r;
}

// W[S][K][Cout] fp32 -> Wt[Npad][Kpad] bf16 (Wt[s*Cout+j][k] = W[s][k][j]; zero pad)
__global__ void wtrans(const float* __restrict__ W, unsigned short* __restrict__ Wt,
                       int S, int K, int Cout, int Npad, int Kpad){
    int idx = blockIdx.x*256 + threadIdx.x;
    if (idx >= Npad*Kpad) return;
    int colp = idx / Kpad, k = idx - colp*Kpad;
    int s = colp / Cout, j = colp - s*Cout;
    float v = 0.f;
    if (s < S && k < K) v = W[((size_t)s*K + k)*Cout + j];
    Wt[idx] = f2bf(v);
}

// ---------------- CSR build ----------------
__global__ void csr_count(const int* __restrict__ dst, int* __restrict__ cnt){
    int e = blockIdx.x*256 + threadIdx.x;
    if (e < EE) atomicAdd(&cnt[dst[e]], 1);
}
__global__ void csr_count0(const int* __restrict__ dst, const int* __restrict__ sel,
                           int* __restrict__ cnt){
    int e = blockIdx.x*256 + threadIdx.x;
    if (e < EE && sel[e] == 0) atomicAdd(&cnt[dst[e]], 1);
}
__global__ void csr_scan(const int* __restrict__ cnt, int* __restrict__ rowptr){
    __shared__ int part[1024];
    int t = threadIdx.x;
    int base = t*16, s = 0;
    int local[16];
    #pragma unroll
    for (int i = 0; i < 16; ++i){ local[i] = s; s += cnt[base+i]; }
    part[t] = s; __syncthreads();
    for (int off = 1; off < 1024; off <<= 1){
        int v = (t >= off) ? part[t-off] : 0;
        __syncthreads();
        part[t] += v;
        __syncthreads();
    }
    int pre = (t == 0) ? 0 : part[t-1];
    #pragma unroll
    for (int i = 0; i < 16; ++i) rowptr[base+i] = pre + local[i];
    if (t == 1023) rowptr[NN] = part[1023];
}
__global__ void csr_fill(const int* __restrict__ src, const int* __restrict__ dst,
                         const int* __restrict__ sel, const int* __restrict__ rowptr,
                         int* __restrict__ cur, int* __restrict__ elist){
    int e = blockIdx.x*256 + threadIdx.x;
    if (e >= EE) return;
    int d = dst[e];
    int p = atomicAdd(&cur[d], 1);
    elist[rowptr[d] + p] = (src[e] << 4) | sel[e];
}
__global__ void csr_fill0(const int* __restrict__ src, const int* __restrict__ dst,
                          const int* __restrict__ sel, const int* __restrict__ rowptr,
                          int* __restrict__ cur, int* __restrict__ elist){
    int e = blockIdx.x*256 + threadIdx.x;
    if (e >= EE || sel[e] != 0) return;
    int d = dst[e];
    int p = atomicAdd(&cur[d], 1);
    elist[rowptr[d] + p] = src[e];
}

// ---------------- MFMA GEMM: C[M,N] = A[M,K] @ Bt[N,K]^T, bf16 in, fp32 acc ----------------
template<typename OutT>
__global__ __launch_bounds__(256, 2)
void mfma_gemm(const unsigned short* __restrict__ A, const unsigned short* __restrict__ Bt,
               OutT* __restrict__ C, int K, int N){
    __shared__ __align__(16) unsigned short As[128*64];
    __shared__ __align__(16) unsigned short Bs[128*64];
    const int tid  = threadIdx.x;
    const int wave = tid >> 6, lane = tid & 63;
    const int row0 = blockIdx.y << 7, col0 = blockIdx.x << 7;
    const int wm = wave >> 1, wn = wave & 1;
    const int fr = lane & 15, fq = lane >> 4;
    f32x4 acc[4][4] = {};
    for (int k0 = 0; k0 < K; k0 += 64){
        __syncthreads();
        #pragma unroll
        for (int i = 0; i < 4; ++i){
            int chb = (wave*4 + i) * 64;
            int ch  = chb + lane;
            int r   = ch >> 3, c8 = ch & 7;
            gload16((const char*)(A  + (size_t)(row0 + r)*K + k0) + c8*16, As + chb*8);
            gload16((const char*)(Bt + (size_t)(col0 + r)*K + k0) + c8*16, Bs + chb*8);
        }
        __syncthreads();
        #pragma unroll
        for (int ks = 0; ks < 2; ++ks){
            bf16x8 av[4], bv[4];
            #pragma unroll
            for (int m = 0; m < 4; ++m)
                av[m] = *(const bf16x8*)(As + ((wm<<6)+(m<<4)+fr)*64 + (ks<<5) + (fq<<3));
            #pragma unroll
            for (int n = 0; n < 4; ++n)
                bv[n] = *(const bf16x8*)(Bs + ((wn<<6)+(n<<4)+fr)*64 + (ks<<5) + (fq<<3));
            #pragma unroll
            for (int m = 0; m < 4; ++m)
                #pragma unroll
                for (int n = 0; n < 4; ++n)
                    acc[m][n] = __builtin_amdgcn_mfma_f32_16x16x32_bf16(av[m], bv[n], acc[m][n], 0, 0, 0);
        }
    }
    #pragma unroll
    for (int m = 0; m < 4; ++m){
        #pragma unroll
        for (int r = 0; r < 4; ++r){
            int row = row0 + (wm<<6) + (m<<4) + (fq<<2) + r;
            OutT* crow = C + (size_t)row*N + col0 + (wn<<6) + fr;
            #pragma unroll
            for (int n = 0; n < 4; ++n){
                float v = acc[m][n][r];
                if constexpr (sizeof(OutT) == 2) crow[n<<4] = f2bf(v);
                else                             crow[n<<4] = v;
            }
        }
    }
}

// ---------------- vectorized CSR gathers ----------------
// 8 bf16 channels per thread. out[d,c0..c0+7] = init + sum over edges.
template<typename TO, bool RELU>
__global__ void gather8(const int* __restrict__ rowptr, const int* __restrict__ elist,
                        const unsigned short* __restrict__ t,
                        const float* __restrict__ bias, const float* __restrict__ initBuf,
                        TO* __restrict__ out, int tStride, int coutShift, int S,
                        int srcLo, int srcHi){
    int idx = blockIdx.x*256 + threadIdx.x;
    int chSh = coutShift - 3;
    int d = idx >> chSh;
    int c0 = (idx & ((1 << chSh) - 1)) << 3;
    float acc[8];
    if (initBuf){
        const float4* ib = (const float4*)(initBuf + ((size_t)d << coutShift) + c0);
        float4 a = ib[0], b = ib[1];
        acc[0]=a.x; acc[1]=a.y; acc[2]=a.z; acc[3]=a.w;
        acc[4]=b.x; acc[5]=b.y; acc[6]=b.z; acc[7]=b.w;
    } else {
        const float4* bb = (const float4*)(bias + c0);
        float4 a = bb[0], b = bb[1];
        acc[0]=a.x; acc[1]=a.y; acc[2]=a.z; acc[3]=a.w;
        acc[4]=b.x; acc[5]=b.y; acc[6]=b.z; acc[7]=b.w;
    }
    int j1 = rowptr[d+1];
    #pragma unroll 2
    for (int j = rowptr[d]; j < j1; ++j){
        int p = elist[j];
        int s = p & 15, sr = p >> 4;
        if (s < S && sr >= srcLo && sr < srcHi){
            bf16x8 v = *(const bf16x8*)(t + (size_t)(sr - srcLo)*tStride + (s << coutShift) + c0);
            #pragma unroll
            for (int k = 0; k < 8; ++k) acc[k] += bf2f((unsigned short)v[k]);
        }
    }
    if (RELU){
        #pragma unroll
        for (int k = 0; k < 8; ++k) acc[k] = fmaxf(acc[k], 0.f);
    }
    if constexpr (sizeof(TO) == 2){
        union { bf16x8 v; unsigned short u[8]; } r;
        #pragma unroll
        for (int k = 0; k < 8; ++k) r.u[k] = f2bf(acc[k]);
        *(bf16x8*)((unsigned short*)out + ((size_t)d << coutShift) + c0) = r.v;
    } else {
        float4 a = {acc[0],acc[1],acc[2],acc[3]};
        float4 b = {acc[4],acc[5],acc[6],acc[7]};
        float4* op = (float4*)((float*)out + ((size_t)d << coutShift) + c0);
        op[0] = a; op[1] = b;
    }
}

// 4 fp32 channels per thread, pre-filtered (sel==0) edge list: elist holds src only.
template<bool ADDV>
__global__ void gather4f(const int* __restrict__ rowptr, const int* __restrict__ elist,
                         const float* __restrict__ t,
                         const float* __restrict__ bias, const float* __restrict__ addvec,
                         float* __restrict__ out, int tStride, int coutShift){
    int idx = blockIdx.x*256 + threadIdx.x;
    int chSh = coutShift - 2;
    int d = idx >> chSh;
    int c0 = (idx & ((1 << chSh) - 1)) << 2;
    float4 bb = *(const float4*)(bias + c0);
    float acc0 = bb.x, acc1 = bb.y, acc2 = bb.z, acc3 = bb.w;
    if (ADDV){
        float4 av = *(const float4*)(addvec + c0);
        acc0 += av.x*(1.f/NN); acc1 += av.y*(1.f/NN);
        acc2 += av.z*(1.f/NN); acc3 += av.w*(1.f/NN);
    }
    int j1 = rowptr[d+1];
    #pragma unroll 2
    for (int j = rowptr[d]; j < j1; ++j){
        int sr = elist[j];
        float4 v = *(const float4*)(t + (size_t)sr*tStride + c0);
        acc0 += v.x; acc1 += v.y; acc2 += v.z; acc3 += v.w;
    }
    float4 r = {acc0, acc1, acc2, acc3};
    *(float4*)(out + ((size_t)d << coutShift) + c0) = r;
}

// ---------------- gram / fc / 32x32 ops ----------------
__global__ void gram_kernel(const float* __restrict__ h, float* __restrict__ g){
    const int RPB = NN/64;
    int r0 = blockIdx.x*RPB;
    int i = threadIdx.x >> 5, j = threadIdx.x & 31;
    float s = 0.f;
    for (int r = 0; r < RPB; ++r){
        const float* row = h + (size_t)(r0+r)*32;
        s += row[i]*row[j];
    }
    atomicAdd(&g[threadIdx.x], s);
}

__global__ void fc_kernel(const float* __restrict__ g, const float* __restrict__ fcW,
                          const float* __restrict__ fcb, float* __restrict__ outMat){
    int i = blockIdx.x;
    float s = 0.f;
    for (int j = threadIdx.x; j < 1024; j += 256)
        s += g[j] * (1.f/NN) * fcW[(size_t)i*1024 + j];
    __shared__ float red[256];
    red[threadIdx.x] = s; __syncthreads();
    for (int off = 128; off > 0; off >>= 1){
        if (threadIdx.x < off) red[threadIdx.x] += red[threadIdx.x+off];
        __syncthreads();
    }
    if (threadIdx.x == 0) outMat[i] = red[0] + fcb[i];
}

__global__ void mm32_kernel(const float* __restrict__ A, const float* __restrict__ B,
                            float* __restrict__ T){
    int i = threadIdx.x >> 5, j = threadIdx.x & 31;
    float s = 0.f;
    for (int k = 0; k < 32; ++k) s += A[i*32+k]*B[k*32+j];
    T[threadIdx.x] = s;
}

// tf fused with bf16 conversion + zero pad: tfbB[n,0..31]=bf16(cc[n]@T^T), [n,32..63]=0
__global__ void tf_cvt_kernel(const float* __restrict__ cc, const float* __restrict__ T,
                              unsigned short* __restrict__ tfbB){
    __shared__ float Ts[1024];
    for (int i = threadIdx.x; i < 1024; i += blockDim.x) Ts[i] = T[i];
    __syncthreads();
    int idx = blockIdx.x*blockDim.x + threadIdx.x;
    int n = idx >> 5, i = idx & 31;
    float s = 0.f;
    const float* crow = cc + (size_t)n*32;
    #pragma unroll
    for (int j = 0; j < 32; ++j) s += crow[j] * Ts[i*32+j];
    tfbB[(size_t)n*64 + i] = f2bf(s);
    tfbB[(size_t)n*64 + 32 + i] = 0;
}

// ---------------- one cnn_net ----------------
static void run_net(hipStream_t st, const unsigned short* xB,
                    const int* rowptr, const int* elist,
                    const unsigned short* W1t, const float* b1,
                    const unsigned short* W2t, const float* b2,
                    const unsigned short* W3t, const float* b3,
                    const float* fcW, const float* fcb,
                    unsigned short* tB,
                    float* h1f, unsigned short* h1b, unsigned short* h2b, float* h3f,
                    float* g, float* outMat){
    // L1: [NN,512] -> 9x256, M split in halves (t = 8192 x 2304 bf16)
    mfma_gemm<unsigned short><<<dim3(18,64),256,0,st>>>(xB, W1t, tB, 512, 2304);
    gather8<float,false><<<NN/8,256,0,st>>>(rowptr,elist,tB,b1,nullptr,h1f,2304,8,9,0,8192);
    mfma_gemm<unsigned short><<<dim3(18,64),256,0,st>>>(xB + (size_t)8192*512, W1t, tB, 512, 2304);
    gather8<unsigned short,true><<<NN/8,256,0,st>>>(rowptr,elist,tB,nullptr,h1f,h1b,2304,8,9,8192,16384);
    // L2: [NN,256] -> 9x128
    mfma_gemm<unsigned short><<<dim3(9,128),256,0,st>>>(h1b, W2t, tB, 256, 1152);
    gather8<unsigned short,true><<<NN/16,256,0,st>>>(rowptr,elist,tB,b2,nullptr,h2b,1152,7,9,0,NN);
    // L3: [NN,128] -> 9x32 (padded to 384)
    mfma_gemm<unsigned short><<<dim3(3,128),256,0,st>>>(h2b, W3t, tB, 128, 384);
    gather8<float,false><<<NN/64,256,0,st>>>(rowptr,elist,tB,b3,nullptr,h3f,384,5,9,0,NN);
    // gram + fc (g pre-zeroed)
    gram_kernel<<<64,1024,0,st>>>(h3f,g);
    fc_kernel<<<1024,256,0,st>>>(g,fcW,fcb,outMat);
}

extern "C" void kernel_launch(void* const* d_in, const int* in_sizes, int n_in,
                              void* d_out, int out_size, void* d_ws, size_t ws_size,
                              hipStream_t stream){
    const float* cF   = (const float*)d_in[0];
    const float* sF   = (const float*)d_in[1];
    const int*   cEI  = (const int*)d_in[2];
    const int*   cSel = (const int*)d_in[3];
    const int*   sEI  = (const int*)d_in[4];
    const int*   sSel = (const int*)d_in[5];
    const float* compW= (const float*)d_in[6];
    const float* compB= (const float*)d_in[7];
    const float* unzW = (const float*)d_in[8];
    const float* unzB = (const float*)d_in[9];
    const float* cW1=(const float*)d_in[10]; const float* cB1=(const float*)d_in[11];
    const float* cW2=(const float*)d_in[12]; const float* cB2=(const float*)d_in[13];
    const float* cW3=(const float*)d_in[14]; const float* cB3=(const float*)d_in[15];
    const float* cFW=(const float*)d_in[16]; const float* cFB=(const float*)d_in[17];
    const float* sW1=(const float*)d_in[18]; const float* sB1=(const float*)d_in[19];
    const float* sW2=(const float*)d_in[20]; const float* sB2=(const float*)d_in[21];
    const float* sW3=(const float*)d_in[22]; const float* sB3=(const float*)d_in[23];
    const float* sFW=(const float*)d_in[24]; const float* sFB=(const float*)d_in[25];

    float* out  = (float*)d_out;
    float* Tmat = out + (size_t)NN*CC;

    // ---- workspace carve ----
    char* w = (char*)d_ws;
    auto alloc = [&](size_t b)->char*{ char* p = w; w += (b + 255) & ~(size_t)255; return p; };
    float* cCol = (float*)alloc(512*4);
    float* sCol = (float*)alloc(512*4);
    float* cg   = (float*)alloc(1024*4);
    float* sg   = (float*)alloc(1024*4);
    float* cMat = (float*)alloc(1024*4);
    float* sMat = (float*)alloc(1024*4);
    int* cCnt = (int*)alloc(NN*4);     // contiguous zero block: 6*NN ints
    int* cCur = (int*)alloc(NN*4);
    int* sCnt = (int*)alloc(NN*4);
    int* sCur = (int*)alloc(NN*4);
    int* cCnt0= (int*)alloc(NN*4);
    int* cCur0= (int*)alloc(NN*4);
    int* cRow = (int*)alloc((NN+1)*4);
    int* sRow = (int*)alloc((NN+1)*4);
    int* cRow0= (int*)alloc((NN+1)*4);
    int* cEl  = (int*)alloc(EE*4);
    int* sEl  = (int*)alloc(EE*4);
    int* cEl0 = (int*)alloc(EE*4);
    float* ccbuf = (float*)alloc((size_t)NN*32*4);
    unsigned short* tfbB = (unsigned short*)alloc((size_t)NN*64*2);
    unsigned short* wtC1 = (unsigned short*)alloc((size_t)2304*512*2);
    unsigned short* wtC2 = (unsigned short*)alloc((size_t)1152*256*2);
    unsigned short* wtC3 = (unsigned short*)alloc((size_t)384*128*2);
    unsigned short* wtS1 = (unsigned short*)alloc((size_t)2304*512*2);
    unsigned short* wtS2 = (unsigned short*)alloc((size_t)1152*256*2);
    unsigned short* wtS3 = (unsigned short*)alloc((size_t)384*128*2);
    unsigned short* wtCo = (unsigned short*)alloc((size_t)128*512*2);
    unsigned short* wtU  = (unsigned short*)alloc((size_t)512*64*2);
    unsigned short* cFcB = (unsigned short*)alloc((size_t)NN*512*2);   // region A
    unsigned short* sFcB = (unsigned short*)alloc((size_t)NN*512*2);
    float* h1f = (float*)alloc((size_t)NN*256*4);
    float* h3f = (float*)alloc((size_t)NN*32*4);
    char*  treg = alloc((size_t)16384*1152*2);
    unsigned short* tB = (unsigned short*)treg;
    float*          tF = (float*)treg;
    unsigned short* h1b = cFcB;                      // overlays (cFcB dead after its GEMMs)
    unsigned short* h2b = cFcB + (size_t)NN*256;

    const int* cSrc = cEI; const int* cDst = cEI + EE;
    const int* sSrc = sEI; const int* sDst = sEI + EE;

    // ---- zero accumulators ----
    zero_f<<<12,256,0,stream>>>((float*)d_ws, 3072);
    zero_i<<<idiv(6*NN,256),256,0,stream>>>(cCnt, 6*NN);

    // ---- means + centering (bf16 out) ----
    colsum4<<<256,128,0,stream>>>(cF, cCol);
    colsum4<<<256,128,0,stream>>>(sF, sCol);
    center_cvt4<<<NN*CC/1024,256,0,stream>>>(cF, cCol, (ushort4*)cFcB);
    center_cvt4<<<NN*CC/1024,256,0,stream>>>(sF, sCol, (ushort4*)sFcB);

    // ---- weight transposes ----
    wtrans<<<idiv(2304*512,256),256,0,stream>>>(cW1, wtC1, 9,512,256, 2304,512);
    wtrans<<<idiv(1152*256,256),256,0,stream>>>(cW2, wtC2, 9,256,128, 1152,256);
    wtrans<<<idiv(384*128,256),256,0,stream>>>(cW3, wtC3, 9,128,32,  384,128);
    wtrans<<<idiv(2304*512,256),256,0,stream>>>(sW1, wtS1, 9,512,256, 2304,512);
    wtrans<<<idiv(1152*256,256),256,0,stream>>>(sW2, wtS2, 9,256,128, 1152,256);
    wtrans<<<idiv(384*128,256),256,0,stream>>>(sW3, wtS3, 9,128,32,  384,128);
    wtrans<<<idiv(128*512,256),256,0,stream>>>(compW, wtCo, 1,512,32, 128,512);
    wtrans<<<idiv(512*64,256),256,0,stream>>>(unzW,  wtU,  1,32,512, 512,64);

    // ---- CSR build ----
    csr_count<<<idiv(EE,256),256,0,stream>>>(cDst, cCnt);
    csr_scan<<<1,1024,0,stream>>>(cCnt, cRow);
    csr_fill<<<idiv(EE,256),256,0,stream>>>(cSrc, cDst, cSel, cRow, cCur, cEl);
    csr_count<<<idiv(EE,256),256,0,stream>>>(sDst, sCnt);
    csr_scan<<<1,1024,0,stream>>>(sCnt, sRow);
    csr_fill<<<idiv(EE,256),256,0,stream>>>(sSrc, sDst, sSel, sRow, sCur, sEl);
    csr_count0<<<idiv(EE,256),256,0,stream>>>(cDst, cSel, cCnt0);
    csr_scan<<<1,1024,0,stream>>>(cCnt0, cRow0);
    csr_fill0<<<idiv(EE,256),256,0,stream>>>(cSrc, cDst, cSel, cRow0, cCur0, cEl0);

    // ---- compress: cc = bias + gather(sel==0) of cFc @ compW ----
    mfma_gemm<float><<<dim3(1,128),256,0,stream>>>(cFcB, wtCo, tF, 512, 128);
    gather4f<false><<<NN*8/256,256,0,stream>>>(cRow0,cEl0,tF,compB,nullptr,ccbuf,128,5);

    // ---- nets ----
    run_net(stream, cFcB, cRow, cEl, wtC1,cB1, wtC2,cB2, wtC3,cB3, cFW,cFB,
            tB, h1f, h1b, h2b, h3f, cg, cMat);
    run_net(stream, sFcB, sRow, sEl, wtS1,sB1, wtS2,sB2, wtS3,sB3, sFW,sFB,
            tB, h1f, h1b, h2b, h3f, sg, sMat);

    // ---- transmatrix + transfeature (fused bf16 cvt+pad) ----
    mm32_kernel<<<1,1024,0,stream>>>(sMat, cMat, Tmat);
    tf_cvt_kernel<<<NN*32/256,256,0,stream>>>(ccbuf, Tmat, tfbB);

    // ---- unzip: out = unzip_b + sMean + gather(sel==0) of tf @ unzip_W ----
    mfma_gemm<float><<<dim3(4,128),256,0,stream>>>(tfbB, wtU, tF, 64, 512);
    gather4f<true><<<NN*128/256,256,0,stream>>>(cRow0,cEl0,tF,unzB,sCol,out,512,9);
}

// Round 4
// 560.093 us; speedup vs baseline: 6.9771x; 1.0171x over previous
//
#include <hip/hip_runtime.h>
#include <hip/hip_bf16.h>
#include <cstddef>
#include <cstdint>

#define NN 16384
#define EE (9*NN)
#define CC 512

typedef __attribute__((ext_vector_type(4))) float f32x4;
typedef __attribute__((ext_vector_type(8))) short bf16x8;

static inline int idiv(int a, int b){ return (a+b-1)/b; }

__device__ __forceinline__ float bf2f(unsigned short u){
    union{unsigned u; float f;} v; v.u = ((unsigned)u) << 16; return v.f;
}
__device__ __forceinline__ unsigned short f2bf(float f){
    union{float f; unsigned u;} v; v.f = f;
    unsigned r = v.u + 0x7fffu + ((v.u >> 16) & 1u);
    return (unsigned short)(r >> 16);
}

__device__ __forceinline__ void gload16(const void* gsrc, void* ldst){
    __builtin_amdgcn_global_load_lds(
        (const __attribute__((address_space(1))) unsigned int*)gsrc,
        (__attribute__((address_space(3))) unsigned int*)ldst,
        16, 0, 0);
}

// ---------------- utility kernels ----------------

__global__ void zero_f(float* __restrict__ p, int n){
    int i = blockIdx.x*256 + threadIdx.x; if (i < n) p[i] = 0.f;
}
__global__ void zero_i(int* __restrict__ p, int n){
    int i = blockIdx.x*256 + threadIdx.x; if (i < n) p[i] = 0;
}

__global__ void colsum4(const float* __restrict__ F, float* __restrict__ cs){
    const int RPB = NN/256;
    int r0 = blockIdx.x * RPB;
    int c4 = threadIdx.x;
    float4 s = {0.f,0.f,0.f,0.f};
    for (int r = 0; r < RPB; ++r){
        float4 v = ((const float4*)(F + (size_t)(r0+r)*CC))[c4];
        s.x += v.x; s.y += v.y; s.z += v.z; s.w += v.w;
    }
    atomicAdd(&cs[c4*4+0], s.x);
    atomicAdd(&cs[c4*4+1], s.y);
    atomicAdd(&cs[c4*4+2], s.z);
    atomicAdd(&cs[c4*4+3], s.w);
}

__global__ void center_cvt4(const float* __restrict__ F, const float* __restrict__ cs,
                            ushort4* __restrict__ o){
    int i = blockIdx.x*256 + threadIdx.x;
    float4 v = ((const float4*)F)[i];
    int c = (i << 2) & (CC-1);
    float4 m = *(const float4*)(cs + c);
    ushort4 r;
    r.x = f2bf(v.x - m.x*(1.f/NN));
    r.y = f2bf(v.y - m.y*(1.f/NN));
    r.z = f2bf(v.z - m.z*(1.f/NN));
    r.w = f2bf(v.w - m.w*(1.f/NN));
    o[i] = r;
}

// generic (slow) weight transpose for small weights
__global__ void wtrans(const float* __restrict__ W, unsigned short* __restrict__ Wt,
                       int S, int K, int Cout, int Npad, int Kpad){
    int idx = blockIdx.x*256 + threadIdx.x;
    if (idx >= Npad*Kpad) return;
    int colp = idx / Kpad, k = idx - colp*Kpad;
    int s = colp / Cout, j = colp - s*Cout;
    float v = 0.f;
    if (s < S && k < K) v = W[((size_t)s*K + k)*Cout + j];
    Wt[idx] = f2bf(v);
}

// fast LDS-tiled transpose: W[S][K][Cout] -> Wt[(s*Cout+j)][k] bf16
// grid (Cout/128, K/32, S), block 128. K mult 32, Cout mult 128.
__global__ void wtrans2(const float* __restrict__ W, unsigned short* __restrict__ Wt,
                        int K, int Cout){
    __shared__ float tile[32][129];
    int jb = blockIdx.x*128, kb = blockIdx.y*32, s = blockIdx.z;
    const float* Ws = W + (size_t)s*K*Cout;
    for (int r = 0; r < 32; ++r)
        tile[r][threadIdx.x] = Ws[(size_t)(kb+r)*Cout + jb + threadIdx.x];
    __syncthreads();
    int kk = threadIdx.x & 31, j0 = threadIdx.x >> 5;
    for (int jj = j0; jj < 128; jj += 4)
        Wt[(size_t)(s*Cout + jb + jj)*K + kb + kk] = f2bf(tile[kk][jj]);
}

// ---------------- CSR build ----------------
__global__ void csr_count(const int* __restrict__ dst, int* __restrict__ cnt){
    int e = blockIdx.x*256 + threadIdx.x;
    if (e < EE) atomicAdd(&cnt[dst[e]], 1);
}
__global__ void csr_count0(const int* __restrict__ dst, const int* __restrict__ sel,
                           int* __restrict__ cnt){
    int e = blockIdx.x*256 + threadIdx.x;
    if (e < EE && sel[e] == 0) atomicAdd(&cnt[dst[e]], 1);
}
__global__ void csr_scan(const int* __restrict__ cnt, int* __restrict__ rowptr){
    __shared__ int part[1024];
    int t = threadIdx.x;
    int base = t*16, s = 0;
    int local[16];
    #pragma unroll
    for (int i = 0; i < 16; ++i){ local[i] = s; s += cnt[base+i]; }
    part[t] = s; __syncthreads();
    for (int off = 1; off < 1024; off <<= 1){
        int v = (t >= off) ? part[t-off] : 0;
        __syncthreads();
        part[t] += v;
        __syncthreads();
    }
    int pre = (t == 0) ? 0 : part[t-1];
    #pragma unroll
    for (int i = 0; i < 16; ++i) rowptr[base+i] = pre + local[i];
    if (t == 1023) rowptr[NN] = part[1023];
}
__global__ void csr_fill(const int* __restrict__ src, const int* __restrict__ dst,
                         const int* __restrict__ sel, const int* __restrict__ rowptr,
                         int* __restrict__ cur, int* __restrict__ elist){
    int e = blockIdx.x*256 + threadIdx.x;
    if (e >= EE) return;
    int d = dst[e];
    int p = atomicAdd(&cur[d], 1);
    elist[rowptr[d] + p] = (src[e] << 4) | sel[e];
}
__global__ void csr_fill0(const int* __restrict__ src, const int* __restrict__ dst,
                          const int* __restrict__ sel, const int* __restrict__ rowptr,
                          int* __restrict__ cur, int* __restrict__ elist){
    int e = blockIdx.x*256 + threadIdx.x;
    if (e >= EE || sel[e] != 0) return;
    int d = dst[e];
    int p = atomicAdd(&cur[d], 1);
    elist[rowptr[d] + p] = src[e];
}

// ---------------- 128^2 MFMA GEMM (proven; small shapes) ----------------
template<typename OutT>
__global__ __launch_bounds__(256, 2)
void mfma_gemm(const unsigned short* __restrict__ A, const unsigned short* __restrict__ Bt,
               OutT* __restrict__ C, int K, int N){
    __shared__ __align__(16) unsigned short As[128*64];
    __shared__ __align__(16) unsigned short Bs[128*64];
    const int tid  = threadIdx.x;
    const int wave = tid >> 6, lane = tid & 63;
    const int row0 = blockIdx.y << 7, col0 = blockIdx.x << 7;
    const int wm = wave >> 1, wn = wave & 1;
    const int fr = lane & 15, fq = lane >> 4;
    f32x4 acc[4][4] = {};
    for (int k0 = 0; k0 < K; k0 += 64){
        __syncthreads();
        #pragma unroll
        for (int i = 0; i < 4; ++i){
            int chb = (wave*4 + i) * 64;
            int ch  = chb + lane;
            int r   = ch >> 3, c8 = ch & 7;
            gload16((const char*)(A  + (size_t)(row0 + r)*K + k0) + c8*16, As + chb*8);
            gload16((const char*)(Bt + (size_t)(col0 + r)*K + k0) + c8*16, Bs + chb*8);
        }
        __syncthreads();
        #pragma unroll
        for (int ks = 0; ks < 2; ++ks){
            bf16x8 av[4], bv[4];
            #pragma unroll
            for (int m = 0; m < 4; ++m)
                av[m] = *(const bf16x8*)(As + ((wm<<6)+(m<<4)+fr)*64 + (ks<<5) + (fq<<3));
            #pragma unroll
            for (int n = 0; n < 4; ++n)
                bv[n] = *(const bf16x8*)(Bs + ((wn<<6)+(n<<4)+fr)*64 + (ks<<5) + (fq<<3));
            #pragma unroll
            for (int m = 0; m < 4; ++m)
                #pragma unroll
                for (int n = 0; n < 4; ++n)
                    acc[m][n] = __builtin_amdgcn_mfma_f32_16x16x32_bf16(av[m], bv[n], acc[m][n], 0, 0, 0);
        }
    }
    #pragma unroll
    for (int m = 0; m < 4; ++m){
        #pragma unroll
        for (int r = 0; r < 4; ++r){
            int row = row0 + (wm<<6) + (m<<4) + (fq<<2) + r;
            OutT* crow = C + (size_t)row*N + col0 + (wn<<6) + fr;
            #pragma unroll
            for (int n = 0; n < 4; ++n){
                float v = acc[m][n][r];
                if constexpr (sizeof(OutT) == 2) crow[n<<4] = f2bf(v);
                else                             crow[n<<4] = v;
            }
        }
    }
}

// ---------------- 256^2 8-phase GEMM (T2+T3+T4+T5), bf16 in/out ----------------
// C[M][N] = A[M][K=NK*64] @ Bt[N][K]^T. M%256==0, N%256==0, grid (N/256, M/256) % 8 == 0.
// LDS: 2 buf x {A0,A1,B0,B1} half-tiles of 128x64 bf16; swizzle byte^=((row&7)<<4)
// applied to BOTH global-source (linear DMA dest) and ds_read addr (involution).
template<int MQ, int NQ>
__device__ __forceinline__ void mfmaq(f32x4 (&acc)[8][4], bf16x8 (&a)[4][2], bf16x8 (&b)[2][2]){
    #pragma unroll
    for (int m = 0; m < 4; ++m)
        #pragma unroll
        for (int n = 0; n < 2; ++n)
            #pragma unroll
            for (int ks = 0; ks < 2; ++ks)
                acc[MQ*4+m][NQ*2+n] = __builtin_amdgcn_mfma_f32_16x16x32_bf16(
                    a[m][ks], b[n][ks], acc[MQ*4+m][NQ*2+n], 0, 0, 0);
}

#define MIDBAR() do{ __builtin_amdgcn_s_barrier(); \
                     asm volatile("s_waitcnt lgkmcnt(0)" ::: "memory"); \
                     __builtin_amdgcn_sched_barrier(0); \
                     __builtin_amdgcn_s_setprio(1); }while(0)
#define ENDBAR() do{ __builtin_amdgcn_s_setprio(0); \
                     __builtin_amdgcn_s_barrier(); }while(0)

template<int NK>
__global__ __launch_bounds__(512, 1)
void gemm8p(const unsigned short* __restrict__ A, const unsigned short* __restrict__ Bt,
            unsigned short* __restrict__ C, int N){
    constexpr int LDK = NK*64;
    __shared__ __align__(16) unsigned short lds[2][4][8192];
    const int tid = threadIdx.x, w = tid >> 6, l = tid & 63;
    // bijective XCD swizzle (nwg % 8 == 0 by construction)
    const int nbx = gridDim.x;
    const int nwg = gridDim.x * gridDim.y;
    int blin = blockIdx.y * nbx + blockIdx.x;
    int sw = (blin & 7) * (nwg >> 3) + (blin >> 3);
    const int bx = sw % nbx, by = sw / nbx;
    const int row0 = by << 8, col0 = bx << 8;
    const int wm = w >> 2, wn = w & 3;
    const int fr = l & 15, fq = l >> 4;

    f32x4 acc[8][4] = {};
    bf16x8 a[4][2], b01[2][2], b23[2][2];

    const unsigned short* gA = A + (size_t)row0 * LDK;
    const unsigned short* gB = Bt + (size_t)col0 * LDK;

    // stage half-tile `half` (0/1) of K-tile t from gbase into ldsHalf (linear DMA
    // dest; source pre-swizzled so physical p holds logical swz(p))
    auto STG = [&](const unsigned short* gbase, int t, int half, unsigned short* ldsHalf){
        #pragma unroll
        for (int s = 0; s < 2; ++s){
            int o = s*8192 + w*1024 + l*16;
            int q = o ^ ((o >> 3) & 0x70);
            int row = q >> 7;
            gload16((const char*)(gbase + (size_t)(half*128 + row)*LDK + t*64) + (q & 127),
                    ldsHalf + s*4096 + w*512);
        }
    };
    // read one A/B fragment: 16-row block rb, k-subtile ks
    auto LDA = [&](const unsigned short* half, int rb, int ks){
        int lg = (rb*16 + fr)*128 + ks*64 + fq*16;
        int ph = lg ^ ((fr & 7) << 4);
        return *(const bf16x8*)((const char*)half + ph);
    };

    // prologue: tile0 fully + B halves of tile1; retire tile0, keep B_1 in flight
    STG(gA, 0, 0, &lds[0][0][0]); STG(gA, 0, 1, &lds[0][1][0]);
    STG(gB, 0, 0, &lds[0][2][0]); STG(gB, 0, 1, &lds[0][3][0]);
    STG(gB, 1, 0, &lds[1][2][0]); STG(gB, 1, 1, &lds[1][3][0]);
    asm volatile("s_waitcnt vmcnt(4)" ::: "memory");
    __builtin_amdgcn_s_barrier();

    const unsigned short* myA[2] = { &lds[0][wm][0], &lds[1][wm][0] };
    const unsigned short* myB[2] = { &lds[0][2+(wn>>1)][0], &lds[1][2+(wn>>1)][0] };
    const int brb = (wn & 1) * 4;

    for (int i = 0; i < NK/2; ++i){
        const int t0 = 2*i, t1 = 2*i + 1;
        // phase 1: (mq0,nq0) buf0 | stage A0_{t1}
        #pragma unroll
        for (int m = 0; m < 4; ++m){ a[m][0] = LDA(myA[0], m, 0); a[m][1] = LDA(myA[0], m, 1); }
        #pragma unroll
        for (int n = 0; n < 2; ++n){ b01[n][0] = LDA(myB[0], brb+n, 0); b01[n][1] = LDA(myB[0], brb+n, 1); }
        STG(gA, t1, 0, &lds[1][0][0]);
        MIDBAR(); mfmaq<0,0>(acc, a, b01); ENDBAR();
        // phase 2: (mq0,nq1) buf0 | stage A1_{t1}
        #pragma unroll
        for (int n = 0; n < 2; ++n){ b23[n][0] = LDA(myB[0], brb+2+n, 0); b23[n][1] = LDA(myB[0], brb+2+n, 1); }
        STG(gA, t1, 1, &lds[1][1][0]);
        MIDBAR(); mfmaq<0,1>(acc, a, b23); ENDBAR();
        // phase 3: (mq1,nq0) buf0 | stage B0_{t0+2}  (buf0 B free after ph2)
        #pragma unroll
        for (int m = 0; m < 4; ++m){ a[m][0] = LDA(myA[0], 4+m, 0); a[m][1] = LDA(myA[0], 4+m, 1); }
        STG(gB, t0+2, 0, &lds[0][2][0]);
        MIDBAR(); mfmaq<1,0>(acc, a, b01); ENDBAR();
        // phase 4: (mq1,nq1) buf0 | stage B1_{t0+2}; counted vmcnt retires tile t1
        STG(gB, t0+2, 1, &lds[0][3][0]);
        asm volatile("s_waitcnt vmcnt(4)" ::: "memory");
        MIDBAR(); mfmaq<1,1>(acc, a, b23); ENDBAR();
        // phase 5: (mq0,nq0) buf1 | stage A0_{t0+2}  (buf0 A free after ph3)
        #pragma unroll
        for (int m = 0; m < 4; ++m){ a[m][0] = LDA(myA[1], m, 0); a[m][1] = LDA(myA[1], m, 1); }
        #pragma unroll
        for (int n = 0; n < 2; ++n){ b01[n][0] = LDA(myB[1], brb+n, 0); b01[n][1] = LDA(myB[1], brb+n, 1); }
        STG(gA, t0+2, 0, &lds[0][0][0]);
        MIDBAR(); mfmaq<0,0>(acc, a, b01); ENDBAR();
        // phase 6: (mq0,nq1) buf1 | stage A1_{t0+2}
        #pragma unroll
        for (int n = 0; n < 2; ++n){ b23[n][0] = LDA(myB[1], brb+2+n, 0); b23[n][1] = LDA(myB[1], brb+2+n, 1); }
        STG(gA, t0+2, 1, &lds[0][1][0]);
        MIDBAR(); mfmaq<0,1>(acc, a, b23); ENDBAR();
        // phase 7: (mq1,nq0) buf1 | stage B0_{t1+2}  (buf1 B free after ph6)
        #pragma unroll
        for (int m = 0; m < 4; ++m){ a[m][0] = LDA(myA[1], 4+m, 0); a[m][1] = LDA(myA[1], 4+m, 1); }
        STG(gB, t1+2, 0, &lds[1][2][0]);
        MIDBAR(); mfmaq<1,0>(acc, a, b01); ENDBAR();
        // phase 8: (mq1,nq1) buf1 | stage B1_{t1+2}; counted vmcnt retires tile t0+2
        STG(gB, t1+2, 1, &lds[1][3][0]);
        asm volatile("s_waitcnt vmcnt(4)" ::: "memory");
        MIDBAR(); mfmaq<1,1>(acc, a, b23); ENDBAR();
    }
    asm volatile("s_waitcnt vmcnt(0)" ::: "memory");

    #pragma unroll
    for (int m = 0; m < 8; ++m){
        #pragma unroll
        for (int r = 0; r < 4; ++r){
            int row = row0 + wm*128 + m*16 + fq*4 + r;
            unsigned short* crow = C + (size_t)row*N + col0 + wn*64 + fr;
            #pragma unroll
            for (int n = 0; n < 4; ++n) crow[n*16] = f2bf(acc[m][n][r]);
        }
    }
}

// ---------------- vectorized CSR gathers ----------------
template<typename TO, bool RELU>
__global__ void gather8(const int* __restrict__ rowptr, const int* __restrict__ elist,
                        const unsigned short* __restrict__ t,
                        const float* __restrict__ bias, const float* __restrict__ initBuf,
                        TO* __restrict__ out, int tStride, int coutShift, int S,
                        int srcLo, int srcHi){
    int idx = blockIdx.x*256 + threadIdx.x;
    int chSh = coutShift - 3;
    int d = idx >> chSh;
    int c0 = (idx & ((1 << chSh) - 1)) << 3;
    float acc[8];
    if (initBuf){
        const float4* ib = (const float4*)(initBuf + ((size_t)d << coutShift) + c0);
        float4 a = ib[0], b = ib[1];
        acc[0]=a.x; acc[1]=a.y; acc[2]=a.z; acc[3]=a.w;
        acc[4]=b.x; acc[5]=b.y; acc[6]=b.z; acc[7]=b.w;
    } else {
        const float4* bb = (const float4*)(bias + c0);
        float4 a = bb[0], b = bb[1];
        acc[0]=a.x; acc[1]=a.y; acc[2]=a.z; acc[3]=a.w;
        acc[4]=b.x; acc[5]=b.y; acc[6]=b.z; acc[7]=b.w;
    }
    int j1 = rowptr[d+1];
    #pragma unroll 2
    for (int j = rowptr[d]; j < j1; ++j){
        int p = elist[j];
        int s = p & 15, sr = p >> 4;
        if (s < S && sr >= srcLo && sr < srcHi){
            bf16x8 v = *(const bf16x8*)(t + (size_t)(sr - srcLo)*tStride + (s << coutShift) + c0);
            #pragma unroll
            for (int k = 0; k < 8; ++k) acc[k] += bf2f((unsigned short)v[k]);
        }
    }
    if (RELU){
        #pragma unroll
        for (int k = 0; k < 8; ++k) acc[k] = fmaxf(acc[k], 0.f);
    }
    if constexpr (sizeof(TO) == 2){
        union { bf16x8 v; unsigned short u[8]; } r;
        #pragma unroll
        for (int k = 0; k < 8; ++k) r.u[k] = f2bf(acc[k]);
        *(bf16x8*)((unsigned short*)out + ((size_t)d << coutShift) + c0) = r.v;
    } else {
        float4 a = {acc[0],acc[1],acc[2],acc[3]};
        float4 b = {acc[4],acc[5],acc[6],acc[7]};
        float4* op = (float4*)((float*)out + ((size_t)d << coutShift) + c0);
        op[0] = a; op[1] = b;
    }
}

template<bool ADDV>
__global__ void gather4f(const int* __restrict__ rowptr, const int* __restrict__ elist,
                         const float* __restrict__ t,
                         const float* __restrict__ bias, const float* __restrict__ addvec,
                         float* __restrict__ out, int tStride, int coutShift){
    int idx = blockIdx.x*256 + threadIdx.x;
    int chSh = coutShift - 2;
    int d = idx >> chSh;
    int c0 = (idx & ((1 << chSh) - 1)) << 2;
    float4 bb = *(const float4*)(bias + c0);
    float acc0 = bb.x, acc1 = bb.y, acc2 = bb.z, acc3 = bb.w;
    if (ADDV){
        float4 av = *(const float4*)(addvec + c0);
        acc0 += av.x*(1.f/NN); acc1 += av.y*(1.f/NN);
        acc2 += av.z*(1.f/NN); acc3 += av.w*(1.f/NN);
    }
    int j1 = rowptr[d+1];
    #pragma unroll 2
    for (int j = rowptr[d]; j < j1; ++j){
        int sr = elist[j];
        float4 v = *(const float4*)(t + (size_t)sr*tStride + c0);
        acc0 += v.x; acc1 += v.y; acc2 += v.z; acc3 += v.w;
    }
    float4 r = {acc0, acc1, acc2, acc3};
    *(float4*)(out + ((size_t)d << coutShift) + c0) = r;
}

// ---------------- gram / fc / 32x32 ops ----------------
__global__ void gram_kernel(const float* __restrict__ h, float* __restrict__ g){
    const int RPB = NN/64;
    int r0 = blockIdx.x*RPB;
    int i = threadIdx.x >> 5, j = threadIdx.x & 31;
    float s = 0.f;
    for (int r = 0; r < RPB; ++r){
        const float* row = h + (size_t)(r0+r)*32;
        s += row[i]*row[j];
    }
    atomicAdd(&g[threadIdx.x], s);
}

__global__ void fc_kernel(const float* __restrict__ g, const float* __restrict__ fcW,
                          const float* __restrict__ fcb, float* __restrict__ outMat){
    int i = blockIdx.x;
    float s = 0.f;
    for (int j = threadIdx.x; j < 1024; j += 256)
        s += g[j] * (1.f/NN) * fcW[(size_t)i*1024 + j];
    __shared__ float red[256];
    red[threadIdx.x] = s; __syncthreads();
    for (int off = 128; off > 0; off >>= 1){
        if (threadIdx.x < off) red[threadIdx.x] += red[threadIdx.x+off];
        __syncthreads();
    }
    if (threadIdx.x == 0) outMat[i] = red[0] + fcb[i];
}

__global__ void mm32_kernel(const float* __restrict__ A, const float* __restrict__ B,
                            float* __restrict__ T){
    int i = threadIdx.x >> 5, j = threadIdx.x & 31;
    float s = 0.f;
    for (int k = 0; k < 32; ++k) s += A[i*32+k]*B[k*32+j];
    T[threadIdx.x] = s;
}

__global__ void tf_cvt_kernel(const float* __restrict__ cc, const float* __restrict__ T,
                              unsigned short* __restrict__ tfbB){
    __shared__ float Ts[1024];
    for (int i = threadIdx.x; i < 1024; i += blockDim.x) Ts[i] = T[i];
    __syncthreads();
    int idx = blockIdx.x*blockDim.x + threadIdx.x;
    int n = idx >> 5, i = idx & 31;
    float s = 0.f;
    const float* crow = cc + (size_t)n*32;
    #pragma unroll
    for (int j = 0; j < 32; ++j) s += crow[j] * Ts[i*32+j];
    tfbB[(size_t)n*64 + i] = f2bf(s);
    tfbB[(size_t)n*64 + 32 + i] = 0;
}

// ---------------- one cnn_net ----------------
static void run_net(hipStream_t st, const unsigned short* xB,
                    const int* rowptr, const int* elist,
                    const unsigned short* W1t, const float* b1,
                    const unsigned short* W2t, const float* b2,
                    const unsigned short* W3t, const float* b3,
                    const float* fcW, const float* fcb,
                    unsigned short* tB,
                    unsigned short* h1b, unsigned short* h2b, float* h3f,
                    float* g, float* outMat){
    // L1: [NN,512] @ [2304,512]^T -> t[NN][2304]; gather -> h1b bf16 [NN][256]
    gemm8p<8><<<dim3(9,64),512,0,st>>>(xB, W1t, tB, 2304);
    gather8<unsigned short,true><<<2048,256,0,st>>>(rowptr,elist,tB,b1,nullptr,h1b,2304,8,9,0,NN);
    // L2: [NN,256] @ [1280,256]^T (cols 1152..1279 pad, never gathered)
    gemm8p<4><<<dim3(5,64),512,0,st>>>(h1b, W2t, tB, 1280);
    gather8<unsigned short,true><<<1024,256,0,st>>>(rowptr,elist,tB,b2,nullptr,h2b,1280,7,9,0,NN);
    // L3: [NN,128] -> 9x32 (padded to 384)
    mfma_gemm<unsigned short><<<dim3(3,128),256,0,st>>>(h2b, W3t, tB, 128, 384);
    gather8<float,false><<<256,256,0,st>>>(rowptr,elist,tB,b3,nullptr,h3f,384,5,9,0,NN);
    gram_kernel<<<64,1024,0,st>>>(h3f,g);
    fc_kernel<<<1024,256,0,st>>>(g,fcW,fcb,outMat);
}

extern "C" void kernel_launch(void* const* d_in, const int* in_sizes, int n_in,
                              void* d_out, int out_size, void* d_ws, size_t ws_size,
                              hipStream_t stream){
    const float* cF   = (const float*)d_in[0];
    const float* sF   = (const float*)d_in[1];
    const int*   cEI  = (const int*)d_in[2];
    const int*   cSel = (const int*)d_in[3];
    const int*   sEI  = (const int*)d_in[4];
    const int*   sSel = (const int*)d_in[5];
    const float* compW= (const float*)d_in[6];
    const float* compB= (const float*)d_in[7];
    const float* unzW = (const float*)d_in[8];
    const float* unzB = (const float*)d_in[9];
    const float* cW1=(const float*)d_in[10]; const float* cB1=(const float*)d_in[11];
    const float* cW2=(const float*)d_in[12]; const float* cB2=(const float*)d_in[13];
    const float* cW3=(const float*)d_in[14]; const float* cB3=(const float*)d_in[15];
    const float* cFW=(const float*)d_in[16]; const float* cFB=(const float*)d_in[17];
    const float* sW1=(const float*)d_in[18]; const float* sB1=(const float*)d_in[19];
    const float* sW2=(const float*)d_in[20]; const float* sB2=(const float*)d_in[21];
    const float* sW3=(const float*)d_in[22]; const float* sB3=(const float*)d_in[23];
    const float* sFW=(const float*)d_in[24]; const float* sFB=(const float*)d_in[25];

    float* out  = (float*)d_out;
    float* Tmat = out + (size_t)NN*CC;

    // ---- workspace carve (~126 MB; ws is 256 MB per fill-kernel evidence) ----
    char* w = (char*)d_ws;
    auto alloc = [&](size_t b)->char*{ char* p = w; w += (b + 255) & ~(size_t)255; return p; };
    float* cCol = (float*)alloc(512*4);
    float* sCol = (float*)alloc(512*4);
    float* cg   = (float*)alloc(1024*4);
    float* sg   = (float*)alloc(1024*4);
    float* cMat = (float*)alloc(1024*4);
    float* sMat = (float*)alloc(1024*4);
    int* cCnt = (int*)alloc(NN*4);     // contiguous zero block: 6*NN ints
    int* cCur = (int*)alloc(NN*4);
    int* sCnt = (int*)alloc(NN*4);
    int* sCur = (int*)alloc(NN*4);
    int* cCnt0= (int*)alloc(NN*4);
    int* cCur0= (int*)alloc(NN*4);
    int* cRow = (int*)alloc((NN+1)*4);
    int* sRow = (int*)alloc((NN+1)*4);
    int* cRow0= (int*)alloc((NN+1)*4);
    int* cEl  = (int*)alloc(EE*4);
    int* sEl  = (int*)alloc(EE*4);
    int* cEl0 = (int*)alloc(EE*4);
    float* ccbuf = (float*)alloc((size_t)NN*32*4);
    unsigned short* tfbB = (unsigned short*)alloc((size_t)NN*64*2);
    unsigned short* wtC1 = (unsigned short*)alloc((size_t)2304*512*2);
    unsigned short* wtC2 = (unsigned short*)alloc((size_t)1280*256*2);
    unsigned short* wtC3 = (unsigned short*)alloc((size_t)384*128*2);
    unsigned short* wtS1 = (unsigned short*)alloc((size_t)2304*512*2);
    unsigned short* wtS2 = (unsigned short*)alloc((size_t)1280*256*2);
    unsigned short* wtS3 = (unsigned short*)alloc((size_t)384*128*2);
    unsigned short* wtCo = (unsigned short*)alloc((size_t)128*512*2);
    unsigned short* wtU  = (unsigned short*)alloc((size_t)512*64*2);
    unsigned short* cFcB = (unsigned short*)alloc((size_t)NN*512*2);   // region A
    unsigned short* sFcB = (unsigned short*)alloc((size_t)NN*512*2);
    float* h3f = (float*)alloc((size_t)NN*32*4);
    char*  treg = alloc((size_t)NN*2304*2);                            // 75.5 MB
    unsigned short* tB = (unsigned short*)treg;
    float*          tF = (float*)treg;
    unsigned short* h1b = cFcB;                      // overlays (cFcB dead after its GEMMs)
    unsigned short* h2b = cFcB + (size_t)NN*256;

    const int* cSrc = cEI; const int* cDst = cEI + EE;
    const int* sSrc = sEI; const int* sDst = sEI + EE;

    // ---- zero accumulators ----
    zero_f<<<12,256,0,stream>>>((float*)d_ws, 3072);
    zero_i<<<idiv(6*NN,256),256,0,stream>>>(cCnt, 6*NN);

    // ---- means + centering (bf16 out) ----
    colsum4<<<256,128,0,stream>>>(cF, cCol);
    colsum4<<<256,128,0,stream>>>(sF, sCol);
    center_cvt4<<<NN*CC/1024,256,0,stream>>>(cF, cCol, (ushort4*)cFcB);
    center_cvt4<<<NN*CC/1024,256,0,stream>>>(sF, sCol, (ushort4*)sFcB);

    // ---- weight transposes ----
    wtrans2<<<dim3(2,16,9),128,0,stream>>>(cW1, wtC1, 512, 256);
    wtrans2<<<dim3(1,8,9),128,0,stream>>>(cW2, wtC2, 256, 128);
    wtrans2<<<dim3(2,16,9),128,0,stream>>>(sW1, wtS1, 512, 256);
    wtrans2<<<dim3(1,8,9),128,0,stream>>>(sW2, wtS2, 256, 128);
    wtrans<<<idiv(384*128,256),256,0,stream>>>(cW3, wtC3, 9,128,32, 384,128);
    wtrans<<<idiv(384*128,256),256,0,stream>>>(sW3, wtS3, 9,128,32, 384,128);
    wtrans<<<idiv(128*512,256),256,0,stream>>>(compW, wtCo, 1,512,32, 128,512);
    wtrans<<<idiv(512*64,256),256,0,stream>>>(unzW,  wtU,  1,32,512, 512,64);

    // ---- CSR build ----
    csr_count<<<idiv(EE,256),256,0,stream>>>(cDst, cCnt);
    csr_scan<<<1,1024,0,stream>>>(cCnt, cRow);
    csr_fill<<<idiv(EE,256),256,0,stream>>>(cSrc, cDst, cSel, cRow, cCur, cEl);
    csr_count<<<idiv(EE,256),256,0,stream>>>(sDst, sCnt);
    csr_scan<<<1,1024,0,stream>>>(sCnt, sRow);
    csr_fill<<<idiv(EE,256),256,0,stream>>>(sSrc, sDst, sSel, sRow, sCur, sEl);
    csr_count0<<<idiv(EE,256),256,0,stream>>>(cDst, cSel, cCnt0);
    csr_scan<<<1,1024,0,stream>>>(cCnt0, cRow0);
    csr_fill0<<<idiv(EE,256),256,0,stream>>>(cSrc, cDst, cSel, cRow0, cCur0, cEl0);

    // ---- compress: cc = bias + gather(sel==0) of cFc @ compW ----
    mfma_gemm<float><<<dim3(1,128),256,0,stream>>>(cFcB, wtCo, tF, 512, 128);
    gather4f<false><<<NN*8/256,256,0,stream>>>(cRow0,cEl0,tF,compB,nullptr,ccbuf,128,5);

    // ---- nets ----
    run_net(stream, cFcB, cRow, cEl, wtC1,cB1, wtC2,cB2, wtC3,cB3, cFW,cFB,
            tB, h1b, h2b, h3f, cg, cMat);
    run_net(stream, sFcB, sRow, sEl, wtS1,sB1, wtS2,sB2, wtS3,sB3, sFW,sFB,
            tB, h1b, h2b, h3f, sg, sMat);

    // ---- transmatrix + transfeature (fused bf16 cvt+pad) ----
    mm32_kernel<<<1,1024,0,stream>>>(sMat, cMat, Tmat);
    tf_cvt_kernel<<<NN*32/256,256,0,stream>>>(ccbuf, Tmat, tfbB);

    // ---- unzip: out = unzip_b + sMean + gather(sel==0) of tf @ unzip_W ----
    mfma_gemm<float><<<dim3(4,128),256,0,stream>>>(tfbB, wtU, tF, 64, 512);
    gather4f<true><<<NN*128/256,256,0,stream>>>(cRow0,cEl0,tF,unzB,sCol,out,512,9);
}

// Round 5
// 438.168 us; speedup vs baseline: 8.9185x; 1.2783x over previous
//
#include <hip/hip_runtime.h>
#include <hip/hip_bf16.h>
#include <cstddef>
#include <cstdint>

#define NN 16384
#define EE (9*NN)
#define CC 512

typedef __attribute__((ext_vector_type(4))) float f32x4;
typedef __attribute__((ext_vector_type(8))) short bf16x8;

static inline int idiv(int a, int b){ return (a+b-1)/b; }

__device__ __forceinline__ float bf2f(unsigned short u){
    union{unsigned u; float f;} v; v.u = ((unsigned)u) << 16; return v.f;
}
__device__ __forceinline__ unsigned short f2bf(float f){
    union{float f; unsigned u;} v; v.f = f;
    unsigned r = v.u + 0x7fffu + ((v.u >> 16) & 1u);
    return (unsigned short)(r >> 16);
}

__device__ __forceinline__ void gload16(const void* gsrc, void* ldst){
    __builtin_amdgcn_global_load_lds(
        (const __attribute__((address_space(1))) unsigned int*)gsrc,
        (__attribute__((address_space(3))) unsigned int*)ldst,
        16, 0, 0);
}

// ---------------- utility kernels ----------------

__global__ void zero_i(int* __restrict__ p, int n){
    int i = blockIdx.x*256 + threadIdx.x; if (i < n) p[i] = 0;
}

// z-merged column sums of F[NN][CC] via float4; cs pre-zeroed.
__global__ void colsum2(const float* __restrict__ F0, float* __restrict__ cs0,
                        const float* __restrict__ F1, float* __restrict__ cs1){
    const float* F = blockIdx.z ? F1 : F0;
    float* cs = blockIdx.z ? cs1 : cs0;
    const int RPB = NN/256;
    int r0 = blockIdx.x * RPB;
    int c4 = threadIdx.x;
    float4 s = {0.f,0.f,0.f,0.f};
    for (int r = 0; r < RPB; ++r){
        float4 v = ((const float4*)(F + (size_t)(r0+r)*CC))[c4];
        s.x += v.x; s.y += v.y; s.z += v.z; s.w += v.w;
    }
    atomicAdd(&cs[c4*4+0], s.x);
    atomicAdd(&cs[c4*4+1], s.y);
    atomicAdd(&cs[c4*4+2], s.z);
    atomicAdd(&cs[c4*4+3], s.w);
}

__global__ void center2(const float* __restrict__ F0, const float* __restrict__ cs0,
                        ushort4* __restrict__ o0,
                        const float* __restrict__ F1, const float* __restrict__ cs1,
                        ushort4* __restrict__ o1){
    const float* F = blockIdx.z ? F1 : F0;
    const float* cs = blockIdx.z ? cs1 : cs0;
    ushort4* o = blockIdx.z ? o1 : o0;
    int i = blockIdx.x*256 + threadIdx.x;
    float4 v = ((const float4*)F)[i];
    int c = (i << 2) & (CC-1);
    float4 m = *(const float4*)(cs + c);
    ushort4 r;
    r.x = f2bf(v.x - m.x*(1.f/NN));
    r.y = f2bf(v.y - m.y*(1.f/NN));
    r.z = f2bf(v.z - m.z*(1.f/NN));
    r.w = f2bf(v.w - m.w*(1.f/NN));
    o[i] = r;
}

// generic (slow) weight transpose for small weights
__global__ void wtrans(const float* __restrict__ W, unsigned short* __restrict__ Wt,
                       int S, int K, int Cout, int Npad, int Kpad){
    int idx = blockIdx.x*256 + threadIdx.x;
    if (idx >= Npad*Kpad) return;
    int colp = idx / Kpad, k = idx - colp*Kpad;
    int s = colp / Cout, j = colp - s*Cout;
    float v = 0.f;
    if (s < S && k < K) v = W[((size_t)s*K + k)*Cout + j];
    Wt[idx] = f2bf(v);
}

// fast LDS-tiled transpose, z-merged over 2 nets x 9 selections
__global__ void wtrans2z(const float* __restrict__ W0, const float* __restrict__ W1,
                         unsigned short* __restrict__ Wt0, unsigned short* __restrict__ Wt1,
                         int K, int Cout){
    __shared__ float tile[32][129];
    int s = blockIdx.z % 9;
    const float* W = (blockIdx.z < 9) ? W0 : W1;
    unsigned short* Wt = (blockIdx.z < 9) ? Wt0 : Wt1;
    int jb = blockIdx.x*128, kb = blockIdx.y*32;
    const float* Ws = W + (size_t)s*K*Cout;
    for (int r = 0; r < 32; ++r)
        tile[r][threadIdx.x] = Ws[(size_t)(kb+r)*Cout + jb + threadIdx.x];
    __syncthreads();
    int kk = threadIdx.x & 31, j0 = threadIdx.x >> 5;
    for (int jj = j0; jj < 128; jj += 4)
        Wt[(size_t)(s*Cout + jb + jj)*K + kb + kk] = f2bf(tile[kk][jj]);
}

// ---------------- CSR build (z-merged: 0=content, 1=style, 2=content sel==0) ----------------
__global__ void csr_count3(const int* __restrict__ cDst, const int* __restrict__ sDst,
                           const int* __restrict__ cSel,
                           int* __restrict__ cCnt, int* __restrict__ sCnt, int* __restrict__ cCnt0){
    int e = blockIdx.x*256 + threadIdx.x;
    if (e >= EE) return;
    int z = blockIdx.z;
    if (z == 0)      atomicAdd(&cCnt[cDst[e]], 1);
    else if (z == 1) atomicAdd(&sCnt[sDst[e]], 1);
    else if (cSel[e] == 0) atomicAdd(&cCnt0[cDst[e]], 1);
}
__global__ void csr_scan3(const int* __restrict__ c0, const int* __restrict__ c1,
                          const int* __restrict__ c2,
                          int* __restrict__ r0, int* __restrict__ r1, int* __restrict__ r2){
    const int* cnt = blockIdx.z==0 ? c0 : (blockIdx.z==1 ? c1 : c2);
    int* rowptr    = blockIdx.z==0 ? r0 : (blockIdx.z==1 ? r1 : r2);
    __shared__ int part[1024];
    int t = threadIdx.x;
    int base = t*16, s = 0;
    int local[16];
    #pragma unroll
    for (int i = 0; i < 16; ++i){ local[i] = s; s += cnt[base+i]; }
    part[t] = s; __syncthreads();
    for (int off = 1; off < 1024; off <<= 1){
        int v = (t >= off) ? part[t-off] : 0;
        __syncthreads();
        part[t] += v;
        __syncthreads();
    }
    int pre = (t == 0) ? 0 : part[t-1];
    #pragma unroll
    for (int i = 0; i < 16; ++i) rowptr[base+i] = pre + local[i];
    if (t == 1023) rowptr[NN] = part[1023];
}
__global__ void csr_fill3(const int* __restrict__ cSrc, const int* __restrict__ cDst,
                          const int* __restrict__ cSel,
                          const int* __restrict__ sSrc, const int* __restrict__ sDst,
                          const int* __restrict__ sSel,
                          const int* __restrict__ cRow, const int* __restrict__ sRow,
                          const int* __restrict__ cRow0,
                          int* __restrict__ cCur, int* __restrict__ sCur, int* __restrict__ cCur0,
                          int* __restrict__ cEl, int* __restrict__ sEl, int* __restrict__ cEl0){
    int e = blockIdx.x*256 + threadIdx.x;
    if (e >= EE) return;
    int z = blockIdx.z;
    if (z == 0){
        int d = cDst[e];
        int p = atomicAdd(&cCur[d], 1);
        cEl[cRow[d] + p] = (cSrc[e] << 4) | cSel[e];
    } else if (z == 1){
        int d = sDst[e];
        int p = atomicAdd(&sCur[d], 1);
        sEl[sRow[d] + p] = (sSrc[e] << 4) | sSel[e];
    } else if (cSel[e] == 0){
        int d = cDst[e];
        int p = atomicAdd(&cCur0[d], 1);
        cEl0[cRow0[d] + p] = cSrc[e];
    }
}

// ---------------- 128^2 MFMA GEMM (2-phase; small shapes), z-selectable ----------------
// swapped-operand accumulator: thread holds C[row=...+fr][col=...+fq*4+r] -> packed stores
template<typename OutT>
__global__ __launch_bounds__(256, 2)
void mfma_gemm(const unsigned short* __restrict__ A0, const unsigned short* __restrict__ Bt0,
               OutT* __restrict__ C0,
               const unsigned short* __restrict__ A1, const unsigned short* __restrict__ Bt1,
               OutT* __restrict__ C1, int K, int N){
    const unsigned short* A  = blockIdx.z ? A1 : A0;
    const unsigned short* Bt = blockIdx.z ? Bt1 : Bt0;
    OutT* C = blockIdx.z ? C1 : C0;
    __shared__ __align__(16) unsigned short As[128*64];
    __shared__ __align__(16) unsigned short Bs[128*64];
    const int tid  = threadIdx.x;
    const int wave = tid >> 6, lane = tid & 63;
    const int row0 = blockIdx.y << 7, col0 = blockIdx.x << 7;
    const int wm = wave >> 1, wn = wave & 1;
    const int fr = lane & 15, fq = lane >> 4;
    f32x4 acc[4][4] = {};
    for (int k0 = 0; k0 < K; k0 += 64){
        __syncthreads();
        #pragma unroll
        for (int i = 0; i < 4; ++i){
            int chb = (wave*4 + i) * 64;
            int ch  = chb + lane;
            int r   = ch >> 3, c8 = ch & 7;
            gload16((const char*)(A  + (size_t)(row0 + r)*K + k0) + c8*16, As + chb*8);
            gload16((const char*)(Bt + (size_t)(col0 + r)*K + k0) + c8*16, Bs + chb*8);
        }
        __syncthreads();
        #pragma unroll
        for (int ks = 0; ks < 2; ++ks){
            bf16x8 av[4], bv[4];
            #pragma unroll
            for (int m = 0; m < 4; ++m)
                av[m] = *(const bf16x8*)(As + ((wm<<6)+(m<<4)+fr)*64 + (ks<<5) + (fq<<3));
            #pragma unroll
            for (int n = 0; n < 4; ++n)
                bv[n] = *(const bf16x8*)(Bs + ((wn<<6)+(n<<4)+fr)*64 + (ks<<5) + (fq<<3));
            #pragma unroll
            for (int m = 0; m < 4; ++m)
                #pragma unroll
                for (int n = 0; n < 4; ++n)
                    acc[m][n] = __builtin_amdgcn_mfma_f32_16x16x32_bf16(bv[n], av[m], acc[m][n], 0, 0, 0);
        }
    }
    #pragma unroll
    for (int m = 0; m < 4; ++m){
        int row = row0 + (wm<<6) + (m<<4) + fr;
        OutT* crow = C + (size_t)row*N + col0 + (wn<<6) + (fq<<2);
        #pragma unroll
        for (int n = 0; n < 4; ++n){
            if constexpr (sizeof(OutT) == 2){
                unsigned lo = f2bf(acc[m][n][0]) | ((unsigned)f2bf(acc[m][n][1]) << 16);
                unsigned hi = f2bf(acc[m][n][2]) | ((unsigned)f2bf(acc[m][n][3]) << 16);
                uint2 pk; pk.x = lo; pk.y = hi;
                *(uint2*)((unsigned short*)crow + (n<<4)) = pk;
            } else {
                float4 pk; pk.x = acc[m][n][0]; pk.y = acc[m][n][1];
                pk.z = acc[m][n][2]; pk.w = acc[m][n][3];
                *(float4*)((float*)crow + (n<<4)) = pk;
            }
        }
    }
}

// ---------------- 256^2 8-phase GEMM (T2+T3+T4+T5), z-selectable ----------------
template<int MQ, int NQ>
__device__ __forceinline__ void mfmaq(f32x4 (&acc)[8][4], bf16x8 (&a)[4][2], bf16x8 (&b)[2][2]){
    #pragma unroll
    for (int m = 0; m < 4; ++m)
        #pragma unroll
        for (int n = 0; n < 2; ++n)
            #pragma unroll
            for (int ks = 0; ks < 2; ++ks)
                acc[MQ*4+m][NQ*2+n] = __builtin_amdgcn_mfma_f32_16x16x32_bf16(
                    b[n][ks], a[m][ks], acc[MQ*4+m][NQ*2+n], 0, 0, 0);
}

#define MIDBAR() do{ __builtin_amdgcn_s_barrier(); \
                     asm volatile("s_waitcnt lgkmcnt(0)" ::: "memory"); \
                     __builtin_amdgcn_sched_barrier(0); \
                     __builtin_amdgcn_s_setprio(1); }while(0)
#define ENDBAR() do{ __builtin_amdgcn_s_setprio(0); \
                     __builtin_amdgcn_s_barrier(); }while(0)

template<int NK>
__global__ __launch_bounds__(512, 1)
void gemm8p(const unsigned short* __restrict__ Ain0, const unsigned short* __restrict__ Btin0,
            unsigned short* __restrict__ Cout0,
            const unsigned short* __restrict__ Ain1, const unsigned short* __restrict__ Btin1,
            unsigned short* __restrict__ Cout1, int N){
    constexpr int LDK = NK*64;
    const unsigned short* A  = blockIdx.z ? Ain1 : Ain0;
    const unsigned short* Bt = blockIdx.z ? Btin1 : Btin0;
    unsigned short* C = blockIdx.z ? Cout1 : Cout0;
    __shared__ __align__(16) unsigned short lds[2][4][8192];
    const int tid = threadIdx.x, w = tid >> 6, l = tid & 63;
    const int nbx = gridDim.x;
    const int nwg = gridDim.x * gridDim.y;
    int blin = blockIdx.y * nbx + blockIdx.x;
    int sw = (blin & 7) * (nwg >> 3) + (blin >> 3);
    const int bx = sw % nbx, by = sw / nbx;
    const int row0 = by << 8, col0 = bx << 8;
    const int wm = w >> 2, wn = w & 3;
    const int fr = l & 15, fq = l >> 4;

    f32x4 acc[8][4] = {};
    bf16x8 a[4][2], b01[2][2], b23[2][2];

    const unsigned short* gA = A + (size_t)row0 * LDK;
    const unsigned short* gB = Bt + (size_t)col0 * LDK;

    auto STG = [&](const unsigned short* gbase, int t, int half, unsigned short* ldsHalf){
        #pragma unroll
        for (int s = 0; s < 2; ++s){
            int o = s*8192 + w*1024 + l*16;
            int q = o ^ ((o >> 3) & 0x70);
            int row = q >> 7;
            gload16((const char*)(gbase + (size_t)(half*128 + row)*LDK + t*64) + (q & 127),
                    ldsHalf + s*4096 + w*512);
        }
    };
    auto LDA = [&](const unsigned short* half, int rb, int ks){
        int lg = (rb*16 + fr)*128 + ks*64 + fq*16;
        int ph = lg ^ ((fr & 7) << 4);
        return *(const bf16x8*)((const char*)half + ph);
    };

    STG(gA, 0, 0, &lds[0][0][0]); STG(gA, 0, 1, &lds[0][1][0]);
    STG(gB, 0, 0, &lds[0][2][0]); STG(gB, 0, 1, &lds[0][3][0]);
    STG(gB, 1, 0, &lds[1][2][0]); STG(gB, 1, 1, &lds[1][3][0]);
    asm volatile("s_waitcnt vmcnt(4)" ::: "memory");
    __builtin_amdgcn_s_barrier();

    const unsigned short* myA[2] = { &lds[0][wm][0], &lds[1][wm][0] };
    const unsigned short* myB[2] = { &lds[0][2+(wn>>1)][0], &lds[1][2+(wn>>1)][0] };
    const int brb = (wn & 1) * 4;

    for (int i = 0; i < NK/2; ++i){
        const int t0 = 2*i, t1 = 2*i + 1;
        #pragma unroll
        for (int m = 0; m < 4; ++m){ a[m][0] = LDA(myA[0], m, 0); a[m][1] = LDA(myA[0], m, 1); }
        #pragma unroll
        for (int n = 0; n < 2; ++n){ b01[n][0] = LDA(myB[0], brb+n, 0); b01[n][1] = LDA(myB[0], brb+n, 1); }
        STG(gA, t1, 0, &lds[1][0][0]);
        MIDBAR(); mfmaq<0,0>(acc, a, b01); ENDBAR();
        #pragma unroll
        for (int n = 0; n < 2; ++n){ b23[n][0] = LDA(myB[0], brb+2+n, 0); b23[n][1] = LDA(myB[0], brb+2+n, 1); }
        STG(gA, t1, 1, &lds[1][1][0]);
        MIDBAR(); mfmaq<0,1>(acc, a, b23); ENDBAR();
        #pragma unroll
        for (int m = 0; m < 4; ++m){ a[m][0] = LDA(myA[0], 4+m, 0); a[m][1] = LDA(myA[0], 4+m, 1); }
        STG(gB, t0+2, 0, &lds[0][2][0]);
        MIDBAR(); mfmaq<1,0>(acc, a, b01); ENDBAR();
        STG(gB, t0+2, 1, &lds[0][3][0]);
        asm volatile("s_waitcnt vmcnt(4)" ::: "memory");
        MIDBAR(); mfmaq<1,1>(acc, a, b23); ENDBAR();
        #pragma unroll
        for (int m = 0; m < 4; ++m){ a[m][0] = LDA(myA[1], m, 0); a[m][1] = LDA(myA[1], m, 1); }
        #pragma unroll
        for (int n = 0; n < 2; ++n){ b01[n][0] = LDA(myB[1], brb+n, 0); b01[n][1] = LDA(myB[1], brb+n, 1); }
        STG(gA, t0+2, 0, &lds[0][0][0]);
        MIDBAR(); mfmaq<0,0>(acc, a, b01); ENDBAR();
        #pragma unroll
        for (int n = 0; n < 2; ++n){ b23[n][0] = LDA(myB[1], brb+2+n, 0); b23[n][1] = LDA(myB[1], brb+2+n, 1); }
        STG(gA, t0+2, 1, &lds[0][1][0]);
        MIDBAR(); mfmaq<0,1>(acc, a, b23); ENDBAR();
        #pragma unroll
        for (int m = 0; m < 4; ++m){ a[m][0] = LDA(myA[1], 4+m, 0); a[m][1] = LDA(myA[1], 4+m, 1); }
        STG(gB, t1+2, 0, &lds[1][2][0]);
        MIDBAR(); mfmaq<1,0>(acc, a, b01); ENDBAR();
        STG(gB, t1+2, 1, &lds[1][3][0]);
        asm volatile("s_waitcnt vmcnt(4)" ::: "memory");
        MIDBAR(); mfmaq<1,1>(acc, a, b23); ENDBAR();
    }
    asm volatile("s_waitcnt vmcnt(0)" ::: "memory");

    // packed epilogue: thread holds rows ...+fr, 4 consecutive cols at fq*4
    #pragma unroll
    for (int m = 0; m < 8; ++m){
        int row = row0 + wm*128 + m*16 + fr;
        unsigned short* crow = C + (size_t)row*N + col0 + wn*64 + fq*4;
        #pragma unroll
        for (int n = 0; n < 4; ++n){
            unsigned lo = f2bf(acc[m][n][0]) | ((unsigned)f2bf(acc[m][n][1]) << 16);
            unsigned hi = f2bf(acc[m][n][2]) | ((unsigned)f2bf(acc[m][n][3]) << 16);
            uint2 pk; pk.x = lo; pk.y = hi;
            *(uint2*)(crow + (n<<4)) = pk;
        }
    }
}

// ---------------- vectorized CSR gathers (z-merged over nets) ----------------
template<typename TO, bool RELU>
__global__ void gather8z(const int* __restrict__ rp0, const int* __restrict__ el0,
                         const unsigned short* __restrict__ t0, const float* __restrict__ b0,
                         TO* __restrict__ o0,
                         const int* __restrict__ rp1, const int* __restrict__ el1,
                         const unsigned short* __restrict__ t1, const float* __restrict__ b1,
                         TO* __restrict__ o1,
                         int tStride, int coutShift){
    const int* rowptr = blockIdx.z ? rp1 : rp0;
    const int* elist  = blockIdx.z ? el1 : el0;
    const unsigned short* t = blockIdx.z ? t1 : t0;
    const float* bias = blockIdx.z ? b1 : b0;
    TO* out = blockIdx.z ? o1 : o0;
    int idx = blockIdx.x*256 + threadIdx.x;
    int chSh = coutShift - 3;
    int d = idx >> chSh;
    int c0 = (idx & ((1 << chSh) - 1)) << 3;
    float acc[8];
    {
        const float4* bb = (const float4*)(bias + c0);
        float4 a = bb[0], b = bb[1];
        acc[0]=a.x; acc[1]=a.y; acc[2]=a.z; acc[3]=a.w;
        acc[4]=b.x; acc[5]=b.y; acc[6]=b.z; acc[7]=b.w;
    }
    int j1 = rowptr[d+1];
    #pragma unroll 2
    for (int j = rowptr[d]; j < j1; ++j){
        int p = elist[j];
        int s = p & 15, sr = p >> 4;
        bf16x8 v = *(const bf16x8*)(t + (size_t)sr*tStride + (s << coutShift) + c0);
        #pragma unroll
        for (int k = 0; k < 8; ++k) acc[k] += bf2f((unsigned short)v[k]);
    }
    if (RELU){
        #pragma unroll
        for (int k = 0; k < 8; ++k) acc[k] = fmaxf(acc[k], 0.f);
    }
    if constexpr (sizeof(TO) == 2){
        union { bf16x8 v; unsigned short u[8]; } r;
        #pragma unroll
        for (int k = 0; k < 8; ++k) r.u[k] = f2bf(acc[k]);
        *(bf16x8*)((unsigned short*)out + ((size_t)d << coutShift) + c0) = r.v;
    } else {
        float4 a = {acc[0],acc[1],acc[2],acc[3]};
        float4 b = {acc[4],acc[5],acc[6],acc[7]};
        float4* op = (float4*)((float*)out + ((size_t)d << coutShift) + c0);
        op[0] = a; op[1] = b;
    }
}

template<bool ADDV>
__global__ void gather4f(const int* __restrict__ rowptr, const int* __restrict__ elist,
                         const float* __restrict__ t,
                         const float* __restrict__ bias, const float* __restrict__ addvec,
                         float* __restrict__ out, int tStride, int coutShift){
    int idx = blockIdx.x*256 + threadIdx.x;
    int chSh = coutShift - 2;
    int d = idx >> chSh;
    int c0 = (idx & ((1 << chSh) - 1)) << 2;
    float4 bb = *(const float4*)(bias + c0);
    float acc0 = bb.x, acc1 = bb.y, acc2 = bb.z, acc3 = bb.w;
    if (ADDV){
        float4 av = *(const float4*)(addvec + c0);
        acc0 += av.x*(1.f/NN); acc1 += av.y*(1.f/NN);
        acc2 += av.z*(1.f/NN); acc3 += av.w*(1.f/NN);
    }
    int j1 = rowptr[d+1];
    #pragma unroll 2
    for (int j = rowptr[d]; j < j1; ++j){
        int sr = elist[j];
        float4 v = *(const float4*)(t + (size_t)sr*tStride + c0);
        acc0 += v.x; acc1 += v.y; acc2 += v.z; acc3 += v.w;
    }
    float4 r = {acc0, acc1, acc2, acc3};
    *(float4*)(out + ((size_t)d << coutShift) + c0) = r;
}

// ---------------- gram / fc / 32x32 ops (z-merged) ----------------
__global__ void gram2(const float* __restrict__ h0, float* __restrict__ g0,
                      const float* __restrict__ h1, float* __restrict__ g1){
    const float* h = blockIdx.z ? h1 : h0;
    float* g = blockIdx.z ? g1 : g0;
    const int RPB = NN/64;
    int r0 = blockIdx.x*RPB;
    int i = threadIdx.x >> 5, j = threadIdx.x & 31;
    float s = 0.f;
    for (int r = 0; r < RPB; ++r){
        const float* row = h + (size_t)(r0+r)*32;
        s += row[i]*row[j];
    }
    atomicAdd(&g[threadIdx.x], s);
}

__global__ void fc2(const float* __restrict__ g0, const float* __restrict__ fcW0,
                    const float* __restrict__ fcb0, float* __restrict__ o0,
                    const float* __restrict__ g1, const float* __restrict__ fcW1,
                    const float* __restrict__ fcb1, float* __restrict__ o1){
    const float* g   = blockIdx.z ? g1 : g0;
    const float* fcW = blockIdx.z ? fcW1 : fcW0;
    const float* fcb = blockIdx.z ? fcb1 : fcb0;
    float* outMat    = blockIdx.z ? o1 : o0;
    int i = blockIdx.x;
    float s = 0.f;
    for (int j = threadIdx.x; j < 1024; j += 256)
        s += g[j] * (1.f/NN) * fcW[(size_t)i*1024 + j];
    __shared__ float red[256];
    red[threadIdx.x] = s; __syncthreads();
    for (int off = 128; off > 0; off >>= 1){
        if (threadIdx.x < off) red[threadIdx.x] += red[threadIdx.x+off];
        __syncthreads();
    }
    if (threadIdx.x == 0) outMat[i] = red[0] + fcb[i];
}

__global__ void mm32_kernel(const float* __restrict__ A, const float* __restrict__ B,
                            float* __restrict__ T){
    int i = threadIdx.x >> 5, j = threadIdx.x & 31;
    float s = 0.f;
    for (int k = 0; k < 32; ++k) s += A[i*32+k]*B[k*32+j];
    T[threadIdx.x] = s;
}

__global__ void tf_cvt_kernel(const float* __restrict__ cc, const float* __restrict__ T,
                              unsigned short* __restrict__ tfbB){
    __shared__ float Ts[1024];
    for (int i = threadIdx.x; i < 1024; i += blockDim.x) Ts[i] = T[i];
    __syncthreads();
    int idx = blockIdx.x*blockDim.x + threadIdx.x;
    int n = idx >> 5, i = idx & 31;
    float s = 0.f;
    const float* crow = cc + (size_t)n*32;
    #pragma unroll
    for (int j = 0; j < 32; ++j) s += crow[j] * Ts[i*32+j];
    tfbB[(size_t)n*64 + i] = f2bf(s);
    tfbB[(size_t)n*64 + 32 + i] = 0;
}

extern "C" void kernel_launch(void* const* d_in, const int* in_sizes, int n_in,
                              void* d_out, int out_size, void* d_ws, size_t ws_size,
                              hipStream_t stream){
    const float* cF   = (const float*)d_in[0];
    const float* sF   = (const float*)d_in[1];
    const int*   cEI  = (const int*)d_in[2];
    const int*   cSel = (const int*)d_in[3];
    const int*   sEI  = (const int*)d_in[4];
    const int*   sSel = (const int*)d_in[5];
    const float* compW= (const float*)d_in[6];
    const float* compB= (const float*)d_in[7];
    const float* unzW = (const float*)d_in[8];
    const float* unzB = (const float*)d_in[9];
    const float* cW1=(const float*)d_in[10]; const float* cB1=(const float*)d_in[11];
    const float* cW2=(const float*)d_in[12]; const float* cB2=(const float*)d_in[13];
    const float* cW3=(const float*)d_in[14]; const float* cB3=(const float*)d_in[15];
    const float* cFW=(const float*)d_in[16]; const float* cFB=(const float*)d_in[17];
    const float* sW1=(const float*)d_in[18]; const float* sB1=(const float*)d_in[19];
    const float* sW2=(const float*)d_in[20]; const float* sB2=(const float*)d_in[21];
    const float* sW3=(const float*)d_in[22]; const float* sB3=(const float*)d_in[23];
    const float* sFW=(const float*)d_in[24]; const float* sFB=(const float*)d_in[25];

    float* out  = (float*)d_out;
    float* Tmat = out + (size_t)NN*CC;

    // ---- workspace carve (~193 MB; ws >= 256 MiB per fill-kernel evidence) ----
    char* w = (char*)d_ws;
    auto alloc = [&](size_t b)->char*{ char* p = w; w += (b + 255) & ~(size_t)255; return p; };
    float* cCol = (float*)alloc(512*4);
    float* sCol = (float*)alloc(512*4);
    float* cg   = (float*)alloc(1024*4);
    float* sg   = (float*)alloc(1024*4);
    float* cMat = (float*)alloc(1024*4);
    float* sMat = (float*)alloc(1024*4);
    int* cCnt = (int*)alloc(NN*4);     // contiguous zero block start (floats above included)
    int* cCur = (int*)alloc(NN*4);
    int* sCnt = (int*)alloc(NN*4);
    int* sCur = (int*)alloc(NN*4);
    int* cCnt0= (int*)alloc(NN*4);
    int* cCur0= (int*)alloc(NN*4);
    int* cRow = (int*)alloc((NN+1)*4);
    int* sRow = (int*)alloc((NN+1)*4);
    int* cRow0= (int*)alloc((NN+1)*4);
    int* cEl  = (int*)alloc(EE*4);
    int* sEl  = (int*)alloc(EE*4);
    int* cEl0 = (int*)alloc(EE*4);
    float* ccbuf = (float*)alloc((size_t)NN*32*4);
    unsigned short* tfbB = (unsigned short*)alloc((size_t)NN*64*2);
    unsigned short* wtC1 = (unsigned short*)alloc((size_t)2304*512*2);
    unsigned short* wtC2 = (unsigned short*)alloc((size_t)1280*256*2);
    unsigned short* wtC3 = (unsigned short*)alloc((size_t)384*128*2);
    unsigned short* wtS1 = (unsigned short*)alloc((size_t)2304*512*2);
    unsigned short* wtS2 = (unsigned short*)alloc((size_t)1280*256*2);
    unsigned short* wtS3 = (unsigned short*)alloc((size_t)384*128*2);
    unsigned short* wtCo = (unsigned short*)alloc((size_t)128*512*2);
    unsigned short* wtU  = (unsigned short*)alloc((size_t)512*64*2);
    unsigned short* cFcB = (unsigned short*)alloc((size_t)NN*512*2);
    unsigned short* sFcB = (unsigned short*)alloc((size_t)NN*512*2);
    float* h3c = (float*)alloc((size_t)NN*32*4);
    float* h3s = (float*)alloc((size_t)NN*32*4);
    unsigned short* tC = (unsigned short*)alloc((size_t)NN*2304*2);
    unsigned short* tS = (unsigned short*)alloc((size_t)NN*2304*2);
    float* tFc = (float*)tC;                        // fp32 views for compress/unzip temps
    // h overlays: cFcB/sFcB dead after L1 GEMM
    unsigned short* h1c = cFcB;
    unsigned short* h1s = sFcB;
    unsigned short* h2c = cFcB + (size_t)NN*256;
    unsigned short* h2s = sFcB + (size_t)NN*256;

    const int* cSrc = cEI; const int* cDst = cEI + EE;
    const int* sSrc = sEI; const int* sDst = sEI + EE;

    // ---- zero the contiguous accumulator block (cCol..cCur0) ----
    int zeroInts = (int)(((char*)cCur0 - (char*)d_ws)/4) + NN;
    zero_i<<<idiv(zeroInts,256),256,0,stream>>>((int*)d_ws, zeroInts);

    // ---- means + centering (bf16 out) ----
    colsum2<<<dim3(256,1,2),128,0,stream>>>(cF, cCol, sF, sCol);
    center2<<<dim3(NN*CC/1024,1,2),256,0,stream>>>(cF, cCol, (ushort4*)cFcB,
                                                   sF, sCol, (ushort4*)sFcB);

    // ---- weight transposes ----
    wtrans2z<<<dim3(2,16,18),128,0,stream>>>(cW1, sW1, wtC1, wtS1, 512, 256);
    wtrans2z<<<dim3(1,8,18),128,0,stream>>>(cW2, sW2, wtC2, wtS2, 256, 128);
    wtrans<<<idiv(384*128,256),256,0,stream>>>(cW3, wtC3, 9,128,32, 384,128);
    wtrans<<<idiv(384*128,256),256,0,stream>>>(sW3, wtS3, 9,128,32, 384,128);
    wtrans<<<idiv(128*512,256),256,0,stream>>>(compW, wtCo, 1,512,32, 128,512);
    wtrans<<<idiv(512*64,256),256,0,stream>>>(unzW,  wtU,  1,32,512, 512,64);

    // ---- CSR build (merged) ----
    csr_count3<<<dim3(idiv(EE,256),1,3),256,0,stream>>>(cDst, sDst, cSel, cCnt, sCnt, cCnt0);
    csr_scan3<<<dim3(1,1,3),1024,0,stream>>>(cCnt, sCnt, cCnt0, cRow, sRow, cRow0);
    csr_fill3<<<dim3(idiv(EE,256),1,3),256,0,stream>>>(cSrc,cDst,cSel, sSrc,sDst,sSel,
                                                       cRow,sRow,cRow0, cCur,sCur,cCur0,
                                                       cEl,sEl,cEl0);

    // ---- compress: cc = bias + gather(sel==0) of cFc @ compW ----
    mfma_gemm<float><<<dim3(1,128,1),256,0,stream>>>(cFcB, wtCo, tFc, cFcB, wtCo, tFc, 512, 128);
    gather4f<false><<<NN*8/256,256,0,stream>>>(cRow0,cEl0,tFc,compB,nullptr,ccbuf,128,5);

    // ---- L1 (both nets) ----
    gemm8p<8><<<dim3(9,64,2),512,0,stream>>>(cFcB, wtC1, tC, sFcB, wtS1, tS, 2304);
    gather8z<unsigned short,true><<<dim3(2048,1,2),256,0,stream>>>(
        cRow,cEl,tC,cB1,h1c, sRow,sEl,tS,sB1,h1s, 2304, 8);
    // ---- L2 (both nets) ----
    gemm8p<4><<<dim3(5,64,2),512,0,stream>>>(h1c, wtC2, tC, h1s, wtS2, tS, 1280);
    gather8z<unsigned short,true><<<dim3(1024,1,2),256,0,stream>>>(
        cRow,cEl,tC,cB2,h2c, sRow,sEl,tS,sB2,h2s, 1280, 7);
    // ---- L3 (both nets) ----
    mfma_gemm<unsigned short><<<dim3(3,128,2),256,0,stream>>>(h2c, wtC3, tC, h2s, wtS3, tS, 128, 384);
    gather8z<float,false><<<dim3(256,1,2),256,0,stream>>>(
        cRow,cEl,tC,cB3,h3c, sRow,sEl,tS,sB3,h3s, 384, 5);
    // ---- gram + fc (both nets) ----
    gram2<<<dim3(64,1,2),1024,0,stream>>>(h3c, cg, h3s, sg);
    fc2<<<dim3(1024,1,2),256,0,stream>>>(cg,cFW,cFB,cMat, sg,sFW,sFB,sMat);

    // ---- transmatrix + transfeature ----
    mm32_kernel<<<1,1024,0,stream>>>(sMat, cMat, Tmat);
    tf_cvt_kernel<<<NN*32/256,256,0,stream>>>(ccbuf, Tmat, tfbB);

    // ---- unzip: out = unzip_b + sMean + gather(sel==0) of tf @ unzip_W ----
    mfma_gemm<float><<<dim3(4,128,1),256,0,stream>>>(tfbB, wtU, tFc, tfbB, wtU, tFc, 64, 512);
    gather4f<true><<<NN*128/256,256,0,stream>>>(cRow0,cEl0,tFc,unzB,sCol,out,512,9);
}